// Round 2
// baseline (1813.579 us; speedup 1.0000x reference)
//
#include <hip/hip_runtime.h>
#include <stdint.h>

typedef __bf16 bf16;
typedef __bf16 bf16x8 __attribute__((ext_vector_type(8)));
typedef __bf16 bf16x4 __attribute__((ext_vector_type(4)));
typedef float  f32x4  __attribute__((ext_vector_type(4)));

#define B_   4
#define S_   1024
#define D_   1024
#define H_   16
#define DH_  64
#define DFF_ 4096
#define NL_  4
#define M_   (B_*S_)   // 4096 rows of activations
#define SPLITK 4

// ---------------------------------------------------------------------------
// async global->LDS copy, 16B per lane. LDS dest is wave-uniform base; lane i
// lands at base + i*16 bytes (guide §5 caveat) — per-lane global addresses.
// ---------------------------------------------------------------------------
__device__ __forceinline__ void async_copy16(const void* g, void* l) {
  __builtin_amdgcn_global_load_lds(
      (const __attribute__((address_space(1))) char*)(uintptr_t)g,
      (__attribute__((address_space(3))) char*)(uintptr_t)l,
      16, 0, 0);
}

// ---------------------------------------------------------------------------
// GEMM (BT form): C[M,N] = A[M,K] @ W[N,K]^T (+ bias), optional relu.
// 128x128 tile, BK=32, 4 waves in 2x2 quadrants, mfma_f32_16x16x32_bf16,
// global_load_lds width=16 staging.
// LDS layout: [kgroup][row] in 16B units (kg = k/8 within the 32-k tile).
//   byte offset = kg*2048 + row*16  -> fragment-read bank = (row*4)%32,
//   consecutive lanes hit distinct 4-bank groups -> 2-way max (free, m136).
// Staging: wave w stages k-group w for all 128 rows of A and of W:
//   2 issues each (rows 0-63, 64-127), per-lane addr = row (bm+half*64+lane).
// MODE: 0 = fp32 out + bias; 1 = bf16 out + bias (+relu); 2 = fp32 split-K
//       partial (no bias), dest Cf + blockIdx.z*M*N, K-range z*Kc..+Kc.
// ---------------------------------------------------------------------------
template<int RELU, int MODE>
__global__ __launch_bounds__(256) void gemm_bt_kernel(
    const bf16* __restrict__ A,     // [M,K] row-major bf16
    const bf16* __restrict__ W,     // [N,K] row-major bf16
    const float* __restrict__ bias, // [N] (MODE 0/1)
    float* __restrict__ Cf,
    bf16*  __restrict__ Cb,
    int N, int K, int Kc)
{
  __shared__ bf16 As[128*32];  // 8KB, [kg][row] 16B units
  __shared__ bf16 Bs[128*32];

  const int tid  = threadIdx.x;
  const int wave = tid >> 6;
  const int lane = tid & 63;
  const int wr = wave >> 1, wc = wave & 1;   // 2x2 wave grid -> 64x64 quadrant
  const int q4  = lane >> 4;                 // quad 0..3
  const int l15 = lane & 15;
  const int bm = blockIdx.y << 7, bn = blockIdx.x << 7;
  const int kz = (MODE == 2) ? blockIdx.z : 0;
  const int kstart = kz * Kc;

  // staging pointers: wave stages k-group `wave`, per-lane row = bm/bn + lane
  const bf16* ag = A + (size_t)(bm + lane)*K + kstart + wave*8;
  const bf16* wg = W + (size_t)(bn + lane)*K + kstart + wave*8;
  bf16* asw = As + wave*1024;   // elements; 2048B strip per kg
  bf16* bsw = Bs + wave*1024;

  // fragment read offsets (elements): kg=q4 strip, row-indexed
  const int a_off = q4*1024 + (wr*64 + l15)*8;
  const int b_off = q4*1024 + (wc*64 + l15)*8;

  f32x4 acc[4][4] = {};

  for (int k0 = 0; k0 < Kc; k0 += 32) {
    async_copy16(ag,                 asw);
    async_copy16(ag + (size_t)64*K,  asw + 512);
    async_copy16(wg,                 bsw);
    async_copy16(wg + (size_t)64*K,  bsw + 512);
    ag += 32; wg += 32;
    __syncthreads();   // drains vmcnt -> staged data visible

    bf16x8 af[4], bfg[4];
#pragma unroll
    for (int r = 0; r < 4; ++r) af[r]  = *(const bf16x8*)(As + a_off + r*16*8);
#pragma unroll
    for (int c = 0; c < 4; ++c) bfg[c] = *(const bf16x8*)(Bs + b_off + c*16*8);
#pragma unroll
    for (int r = 0; r < 4; ++r)
#pragma unroll
      for (int c = 0; c < 4; ++c)
        acc[r][c] = __builtin_amdgcn_mfma_f32_16x16x32_bf16(af[r], bfg[c], acc[r][c], 0, 0, 0);
    __syncthreads();   // all reads done before next stage overwrites
  }

  // epilogue: C/D layout col=lane&15, row=quad*4+reg (m89-verified)
  float* Cfz = (MODE == 2) ? (Cf + (size_t)kz * ((size_t)M_ * N)) : Cf;
#pragma unroll
  for (int r = 0; r < 4; ++r) {
    const int row0 = bm + wr*64 + r*16 + q4*4;
#pragma unroll
    for (int c = 0; c < 4; ++c) {
      const int col = bn + wc*64 + c*16 + l15;
      const float bv = (MODE == 2) ? 0.f : bias[col];
#pragma unroll
      for (int i = 0; i < 4; ++i) {
        float v = acc[r][c][i] + bv;
        if (RELU) v = fmaxf(v, 0.f);
        if (MODE == 1) Cb[(size_t)(row0 + i)*N + col] = (bf16)v;
        else           Cfz[(size_t)(row0 + i)*N + col] = v;
      }
    }
  }
}

// ---------------------------------------------------------------------------
// Flash-style block-causal attention. One workgroup per (qblock, b*H+h).
// BLK==64 == tile, so no intra-tile masking.
// ---------------------------------------------------------------------------
#define LP 72
__global__ __launch_bounds__(256) void attn_kernel(
    const bf16* __restrict__ qkv,  // [M, 3*D] rows b*S+s; Q|K|V col blocks
    bf16* __restrict__ out)        // [M, D]
{
  const int qb  = blockIdx.x;          // 0..15
  const int bh  = blockIdx.y;          // 0..63
  const int b   = bh >> 4, h = bh & 15;
  const int tid = threadIdx.x;
  const int wave = tid >> 6, lane = tid & 63;
  const int q4 = lane >> 4, l15 = lane & 15;

  __shared__ bf16 Qs[64*LP];
  __shared__ bf16 Ks[64*LP];
  __shared__ bf16 Vt[64*LP];       // transposed: Vt[d][n]
  __shared__ bf16 Ps[4][16*LP];    // per-wave P strip (C-layout -> A-layout)

  const size_t RS = 3*(size_t)D_;  // qkv row stride
  const bf16* qbase = qkv + ((size_t)(b*S_ + qb*64))*RS + h*64;

  {
    int cidx = tid;
#pragma unroll
    for (int it = 0; it < 2; ++it, cidx += 256) {
      int r = cidx >> 3, co = (cidx & 7)*8;
      *(bf16x8*)&Qs[r*LP + co] = *(const bf16x8*)&qbase[(size_t)r*RS + co];
    }
  }

  f32x4 o_acc[4] = {};
  float m_i[4], l_i[4];
#pragma unroll
  for (int i = 0; i < 4; ++i) { m_i[i] = -1e30f; l_i[i] = 0.f; }
  const float scale = 0.125f;   // 1/sqrt(64)

  for (int kt = 0; kt <= qb; ++kt) {
    __syncthreads();
    const bf16* kbase = qkv + ((size_t)(b*S_ + kt*64))*RS + D_   + h*64;
    const bf16* vbase = qkv + ((size_t)(b*S_ + kt*64))*RS + 2*D_ + h*64;
    {
      int cidx = tid;
#pragma unroll
      for (int it = 0; it < 2; ++it, cidx += 256) {
        int r = cidx >> 3, co = (cidx & 7)*8;
        *(bf16x8*)&Ks[r*LP + co] = *(const bf16x8*)&kbase[(size_t)r*RS + co];
        bf16x8 v = *(const bf16x8*)&vbase[(size_t)r*RS + co];
#pragma unroll
        for (int j = 0; j < 8; ++j) Vt[(co + j)*LP + r] = v[j];
      }
    }
    __syncthreads();

    // S = Q @ K^T  (wave covers 16 query rows: wave*16 + l15)
    f32x4 s[4] = {};
#pragma unroll
    for (int d0 = 0; d0 < 64; d0 += 32) {
      bf16x8 aq = *(const bf16x8*)&Qs[(wave*16 + l15)*LP + d0 + q4*8];
#pragma unroll
      for (int c = 0; c < 4; ++c) {
        bf16x8 bk = *(const bf16x8*)&Ks[(c*16 + l15)*LP + d0 + q4*8];
        s[c] = __builtin_amdgcn_mfma_f32_16x16x32_bf16(aq, bk, s[c], 0, 0, 0);
      }
    }
#pragma unroll
    for (int c = 0; c < 4; ++c)
#pragma unroll
      for (int i = 0; i < 4; ++i) s[c][i] *= scale;

    // online softmax per register-row i (row = wave*16 + q4*4 + i)
#pragma unroll
    for (int i = 0; i < 4; ++i) {
      float mx = -1e30f;
#pragma unroll
      for (int c = 0; c < 4; ++c) mx = fmaxf(mx, s[c][i]);
#pragma unroll
      for (int off = 1; off < 16; off <<= 1) mx = fmaxf(mx, __shfl_xor(mx, off, 64));
      float m_new = fmaxf(m_i[i], mx);
      float alpha = __expf(m_i[i] - m_new);
      float rowsum = 0.f;
#pragma unroll
      for (int c = 0; c < 4; ++c) {
        float p = __expf(s[c][i] - m_new);
        Ps[wave][(q4*4 + i)*LP + c*16 + l15] = (bf16)p;
        rowsum += p;
      }
#pragma unroll
      for (int off = 1; off < 16; off <<= 1) rowsum += __shfl_xor(rowsum, off, 64);
      l_i[i] = l_i[i]*alpha + rowsum;
      m_i[i] = m_new;
#pragma unroll
      for (int c = 0; c < 4; ++c) o_acc[c][i] *= alpha;
    }

    // O += P @ V   (Ps is wave-private)
#pragma unroll
    for (int n0 = 0; n0 < 64; n0 += 32) {
      bf16x8 ap = *(const bf16x8*)&Ps[wave][l15*LP + n0 + q4*8];
#pragma unroll
      for (int c = 0; c < 4; ++c) {
        bf16x8 bv = *(const bf16x8*)&Vt[(c*16 + l15)*LP + n0 + q4*8];
        o_acc[c] = __builtin_amdgcn_mfma_f32_16x16x32_bf16(ap, bv, o_acc[c], 0, 0, 0);
      }
    }
  }

  bf16* obase = out + ((size_t)(b*S_ + qb*64 + wave*16))*D_ + h*64;
#pragma unroll
  for (int i = 0; i < 4; ++i) {
    float inv = 1.f / l_i[i];
#pragma unroll
    for (int c = 0; c < 4; ++c)
      obase[(size_t)(q4*4 + i)*D_ + c*16 + l15] = (bf16)(o_acc[c][i]*inv);
  }
}

// ---------------------------------------------------------------------------
// fused: split-K reduce (+bias) + residual add + LayerNorm (fp32 stats).
// y = sum_{p<4} parts[p][row] + ybias;  x = LN(xin + y) -> fp32, bf16, extra
// ---------------------------------------------------------------------------
__global__ __launch_bounds__(256) void add_ln_kernel(
    const float* __restrict__ xin, const float* __restrict__ parts,
    const float* __restrict__ ybias,
    const float* __restrict__ w, const float* __restrict__ bta,
    float* __restrict__ xout, bf16* __restrict__ xbf,
    float* __restrict__ extra)
{
  const int row = blockIdx.x;
  const int tid = threadIdx.x;
  const size_t base = (size_t)row * D_;
  const size_t PS = (size_t)M_ * D_;
  float v[4], s = 0.f, ss = 0.f;
#pragma unroll
  for (int j = 0; j < 4; ++j) {
    int idx = tid + j*256;
    float y = ybias[idx];
#pragma unroll
    for (int p = 0; p < SPLITK; ++p) y += parts[p*PS + base + idx];
    v[j] = xin[base + idx] + y;
    s += v[j]; ss += v[j]*v[j];
  }
#pragma unroll
  for (int off = 1; off < 64; off <<= 1) {
    s  += __shfl_xor(s,  off, 64);
    ss += __shfl_xor(ss, off, 64);
  }
  __shared__ float red[8];
  const int wave = tid >> 6, lane = tid & 63;
  if (lane == 0) { red[wave] = s; red[4 + wave] = ss; }
  __syncthreads();
  s  = red[0] + red[1] + red[2] + red[3];
  ss = red[4] + red[5] + red[6] + red[7];
  const float mean = s * (1.f/D_);
  const float var  = ss * (1.f/D_) - mean*mean;
  const float rstd = rsqrtf(var + 1e-5f);
#pragma unroll
  for (int j = 0; j < 4; ++j) {
    int idx = tid + j*256;
    float o = (v[j] - mean)*rstd*w[idx] + bta[idx];
    xout[base + idx] = o;
    xbf[base + idx]  = (bf16)o;
    if (extra) extra[base + idx] = o;
  }
}

// ---------------------------------------------------------------------------
__global__ __launch_bounds__(256) void conv_kernel(
    const float4* __restrict__ src, bf16x4* __restrict__ dst, int n4)
{
  int i = blockIdx.x*blockDim.x + threadIdx.x;
  const int stride = gridDim.x*blockDim.x;
  for (; i < n4; i += stride) {
    float4 f = src[i];
    bf16x4 o;
    o[0] = (bf16)f.x; o[1] = (bf16)f.y; o[2] = (bf16)f.z; o[3] = (bf16)f.w;
    dst[i] = o;
  }
}

__global__ __launch_bounds__(256) void init_x_kernel(
    const float4* __restrict__ src, float4* __restrict__ xf,
    bf16x4* __restrict__ xb, int n4)
{
  int i = blockIdx.x*blockDim.x + threadIdx.x;
  const int stride = gridDim.x*blockDim.x;
  for (; i < n4; i += stride) {
    float4 f = src[i];
    xf[i] = f;
    bf16x4 o;
    o[0] = (bf16)f.x; o[1] = (bf16)f.y; o[2] = (bf16)f.z; o[3] = (bf16)f.w;
    xb[i] = o;
  }
}

// ---------------------------------------------------------------------------
extern "C" void kernel_launch(void* const* d_in, const int* in_sizes, int n_in,
                              void* d_out, int out_size, void* d_ws, size_t ws_size,
                              hipStream_t stream) {
  const float* x    = (const float*)d_in[0];
  const float* inw  = (const float*)d_in[1];
  const float* inb  = (const float*)d_in[2];
  const float* outw = (const float*)d_in[3];
  const float* outb = (const float*)d_in[4];
  const float* ln1w = (const float*)d_in[5];
  const float* ln1b = (const float*)d_in[6];
  const float* l1w  = (const float*)d_in[7];
  const float* l1b  = (const float*)d_in[8];
  const float* l2w  = (const float*)d_in[9];
  const float* l2b  = (const float*)d_in[10];
  const float* ln2w = (const float*)d_in[11];
  const float* ln2b = (const float*)d_in[12];

  char* ws = (char*)d_ws;
  size_t off = 0;
  auto take = [&](size_t bytes) {
    char* p = ws + off;
    off = (off + bytes + 255) & ~(size_t)255;
    return p;
  };
  bf16*  w_in_bf  = (bf16*) take((size_t)NL_*3*D_*D_*2);
  bf16*  w_out_bf = (bf16*) take((size_t)NL_*D_*D_*2);
  bf16*  w_l1_bf  = (bf16*) take((size_t)NL_*DFF_*D_*2);
  bf16*  w_l2_bf  = (bf16*) take((size_t)NL_*D_*DFF_*2);
  float* x_f      = (float*)take((size_t)M_*D_*4);
  bf16*  x_b      = (bf16*) take((size_t)M_*D_*2);
  bf16*  qkv_b    = (bf16*) take((size_t)M_*3*D_*2);
  bf16*  at_b     = (bf16*) take((size_t)M_*D_*2);
  bf16*  h_b      = (bf16*) take((size_t)M_*DFF_*2);
  float* parts    = (float*)take((size_t)SPLITK*M_*D_*4);
  (void)ws_size; (void)in_sizes; (void)n_in;

  auto conv = [&](const float* s, bf16* d, size_t n) {
    int n4 = (int)(n >> 2);
    int grid = (n4 + 255) / 256; if (grid > 4096) grid = 4096;
    conv_kernel<<<grid, 256, 0, stream>>>((const float4*)s, (bf16x4*)d, n4);
  };
  conv(inw,  w_in_bf,  (size_t)NL_*3*D_*D_);
  conv(outw, w_out_bf, (size_t)NL_*D_*D_);
  conv(l1w,  w_l1_bf,  (size_t)NL_*DFF_*D_);
  conv(l2w,  w_l2_bf,  (size_t)NL_*D_*DFF_);
  init_x_kernel<<<4096, 256, 0, stream>>>((const float4*)x, (float4*)x_f,
                                          (bf16x4*)x_b, (int)((size_t)M_*D_ >> 2));

  for (int l = 0; l < NL_; ++l) {
    // qkv = x @ in_proj_w^T + b   [4096,3072] bf16
    gemm_bt_kernel<0,1><<<dim3(3*D_/128, M_/128), 256, 0, stream>>>(
        x_b, w_in_bf + (size_t)l*3*D_*D_, inb + (size_t)l*3*D_,
        nullptr, qkv_b, 3*D_, D_, D_);
    // attention -> at_b [4096,1024] bf16
    attn_kernel<<<dim3(S_/64, B_*H_), 256, 0, stream>>>(qkv_b, at_b);
    // o_partials = attn @ out_w^T  (split-K=4, Kc=256)
    gemm_bt_kernel<0,2><<<dim3(D_/128, M_/128, SPLITK), 256, 0, stream>>>(
        at_b, w_out_bf + (size_t)l*D_*D_, nullptr,
        parts, nullptr, D_, D_, D_/SPLITK);
    // x = LN(x + sum(parts) + out_b)
    add_ln_kernel<<<M_, 256, 0, stream>>>(
        x_f, parts, outb + (size_t)l*D_,
        ln1w + (size_t)l*D_, ln1b + (size_t)l*D_, x_f, x_b, nullptr);
    // h = relu(x @ lin1^T + b) [4096,4096] bf16
    gemm_bt_kernel<1,1><<<dim3(DFF_/128, M_/128), 256, 0, stream>>>(
        x_b, w_l1_bf + (size_t)l*DFF_*D_, l1b + (size_t)l*DFF_,
        nullptr, h_b, DFF_, D_, D_);
    // f_partials = h @ lin2^T  (split-K=4, Kc=1024)
    gemm_bt_kernel<0,2><<<dim3(D_/128, M_/128, SPLITK), 256, 0, stream>>>(
        h_b, w_l2_bf + (size_t)l*D_*DFF_, nullptr,
        parts, nullptr, D_, DFF_, DFF_/SPLITK);
    // x = LN(x + sum(parts) + lin2_b); last layer also writes d_out
    add_ln_kernel<<<M_, 256, 0, stream>>>(
        x_f, parts, l2b + (size_t)l*D_,
        ln2w + (size_t)l*D_, ln2b + (size_t)l*D_, x_f, x_b,
        (l == NL_-1) ? (float*)d_out : nullptr);
  }
}

// Round 3
// 1746.891 us; speedup vs baseline: 1.0382x; 1.0382x over previous
//
#include <hip/hip_runtime.h>
#include <stdint.h>

typedef __bf16 bf16;
typedef __bf16 bf16x8 __attribute__((ext_vector_type(8)));
typedef __bf16 bf16x4 __attribute__((ext_vector_type(4)));
typedef float  f32x4  __attribute__((ext_vector_type(4)));

#define B_   4
#define S_   1024
#define D_   1024
#define H_   16
#define DH_  64
#define DFF_ 4096
#define NL_  4
#define M_   (B_*S_)   // 4096 rows of activations

// ---------------------------------------------------------------------------
// async global->LDS copy, 16B per lane. LDS dest is wave-uniform base; lane i
// lands at base + i*16 bytes (guide §5 caveat).
// ---------------------------------------------------------------------------
__device__ __forceinline__ void async_copy16(const void* g, void* l) {
  __builtin_amdgcn_global_load_lds(
      (const __attribute__((address_space(1))) char*)(uintptr_t)g,
      (__attribute__((address_space(3))) char*)(uintptr_t)l,
      16, 0, 0);
}

// ---------------------------------------------------------------------------
// GEMM (BT form): C[M,N] = A[M,K] @ W[N,K]^T + bias, optional relu.
// Tile: 128(M) x TN(N), BK=32, 4 waves. TN=128: waves 2x2 over 64x64.
// TN=64: waves 2x2 over 64x32 -> 512 blocks for N=1024 (2 blocks/CU, two
// independent barrier groups per CU).
// LDS layout [kg][row] in 16B units: fragment-read bank = (row*4)%32 ->
// <=2-way conflicts (free, m136; verified 0 conflicts in round 2).
// XCD swizzle: linear block L -> xcd = L&7 (round-robin heuristic), slot
// s = L>>3; each XCD owns a contiguous PN x PM patch of (bn,bm) tiles so
// its L2 working set is ~PN*Wstrip + PM*Astrip instead of all of A.
// Requires grid == 8*PN*PM, gx%PN==0, (gx/PN)*(gy/PM)==8.
// ---------------------------------------------------------------------------
template<int RELU, int OUT_BF16, int TN>
__global__ __launch_bounds__(256) void gemm_bt_kernel(
    const bf16* __restrict__ A,     // [M,K] row-major bf16
    const bf16* __restrict__ W,     // [N,K] row-major bf16
    const float* __restrict__ bias, // [N]
    float* __restrict__ Cf,         // used if !OUT_BF16
    bf16*  __restrict__ Cb,         // used if OUT_BF16
    int N, int K, int gx, int PN, int PM)
{
  constexpr int WCW = TN / 2;       // wave column width (64 or 32)
  constexpr int NC  = WCW / 16;     // col fragments per wave (4 or 2)

  __shared__ bf16 As[128*32];       // [kg][128 rows][8k]
  __shared__ bf16 Bs[TN*32];        // [kg][TN rows][8k]

  const int tid  = threadIdx.x;
  const int wave = tid >> 6;
  const int lane = tid & 63;
  const int wr = wave >> 1, wc = wave & 1;
  const int q4  = lane >> 4;
  const int l15 = lane & 15;

  // XCD-patch swizzle
  const int L   = blockIdx.x;
  const int xcd = L & 7;
  const int s   = L >> 3;
  const int Gn  = gx / PN;
  const int bn_t = (xcd % Gn)*PN + (s % PN);
  const int bm_t = (xcd / Gn)*PM + (s / PN);
  const int bm = bm_t << 7;
  const int bn = bn_t * TN;

  // staging: wave w stages k-group w. A: 128 rows = 2 issues; B: TN rows.
  const bf16* ag = A + (size_t)(bm + lane)*K + wave*8;
  const bf16* wg = W + (size_t)(bn + lane)*K + wave*8;
  bf16* asw = As + wave*1024;       // 128 rows * 8 elem
  bf16* bsw = Bs + wave*(TN*8);

  const int a_off = q4*1024    + (wr*64  + l15)*8;
  const int b_off = q4*(TN*8)  + (wc*WCW + l15)*8;

  f32x4 acc[4][NC] = {};

  for (int k0 = 0; k0 < K; k0 += 32) {
    async_copy16(ag,                asw);
    async_copy16(ag + (size_t)64*K, asw + 512);
    async_copy16(wg,                bsw);
    if (TN == 128)
      async_copy16(wg + (size_t)64*K, bsw + 512);
    ag += 32; wg += 32;
    __syncthreads();   // drains vmcnt -> staged data visible

    bf16x8 af[4], bfg[NC];
#pragma unroll
    for (int r = 0; r < 4; ++r)  af[r]  = *(const bf16x8*)(As + a_off + r*16*8);
#pragma unroll
    for (int c = 0; c < NC; ++c) bfg[c] = *(const bf16x8*)(Bs + b_off + c*16*8);
#pragma unroll
    for (int r = 0; r < 4; ++r)
#pragma unroll
      for (int c = 0; c < NC; ++c)
        acc[r][c] = __builtin_amdgcn_mfma_f32_16x16x32_bf16(af[r], bfg[c], acc[r][c], 0, 0, 0);
    __syncthreads();   // all reads done before next stage overwrites
  }

  // epilogue: C/D layout col=lane&15, row=quad*4+reg (m89-verified)
#pragma unroll
  for (int r = 0; r < 4; ++r) {
    const int row0 = bm + wr*64 + r*16 + q4*4;
#pragma unroll
    for (int c = 0; c < NC; ++c) {
      const int col = bn + wc*WCW + c*16 + l15;
      const float bv = bias[col];
#pragma unroll
      for (int i = 0; i < 4; ++i) {
        float v = acc[r][c][i] + bv;
        if (RELU) v = fmaxf(v, 0.f);
        if (OUT_BF16) Cb[(size_t)(row0 + i)*N + col] = (bf16)v;
        else          Cf[(size_t)(row0 + i)*N + col] = v;
      }
    }
  }
}

// ---------------------------------------------------------------------------
// Flash-style block-causal attention. One workgroup per (qblock, b*H+h).
// BLK==64 == tile, so no intra-tile masking.
// ---------------------------------------------------------------------------
#define LP 72
__global__ __launch_bounds__(256) void attn_kernel(
    const bf16* __restrict__ qkv,  // [M, 3*D] rows b*S+s; Q|K|V col blocks
    bf16* __restrict__ out)        // [M, D]
{
  const int qb  = blockIdx.x;          // 0..15
  const int bh  = blockIdx.y;          // 0..63
  const int b   = bh >> 4, h = bh & 15;
  const int tid = threadIdx.x;
  const int wave = tid >> 6, lane = tid & 63;
  const int q4 = lane >> 4, l15 = lane & 15;

  __shared__ bf16 Qs[64*LP];
  __shared__ bf16 Ks[64*LP];
  __shared__ bf16 Vt[64*LP];       // transposed: Vt[d][n]
  __shared__ bf16 Ps[4][16*LP];    // per-wave P strip (C-layout -> A-layout)

  const size_t RS = 3*(size_t)D_;
  const bf16* qbase = qkv + ((size_t)(b*S_ + qb*64))*RS + h*64;

  {
    int cidx = tid;
#pragma unroll
    for (int it = 0; it < 2; ++it, cidx += 256) {
      int r = cidx >> 3, co = (cidx & 7)*8;
      *(bf16x8*)&Qs[r*LP + co] = *(const bf16x8*)&qbase[(size_t)r*RS + co];
    }
  }

  f32x4 o_acc[4] = {};
  float m_i[4], l_i[4];
#pragma unroll
  for (int i = 0; i < 4; ++i) { m_i[i] = -1e30f; l_i[i] = 0.f; }
  const float scale = 0.125f;   // 1/sqrt(64)

  for (int kt = 0; kt <= qb; ++kt) {
    __syncthreads();
    const bf16* kbase = qkv + ((size_t)(b*S_ + kt*64))*RS + D_   + h*64;
    const bf16* vbase = qkv + ((size_t)(b*S_ + kt*64))*RS + 2*D_ + h*64;
    {
      int cidx = tid;
#pragma unroll
      for (int it = 0; it < 2; ++it, cidx += 256) {
        int r = cidx >> 3, co = (cidx & 7)*8;
        *(bf16x8*)&Ks[r*LP + co] = *(const bf16x8*)&kbase[(size_t)r*RS + co];
        bf16x8 v = *(const bf16x8*)&vbase[(size_t)r*RS + co];
#pragma unroll
        for (int j = 0; j < 8; ++j) Vt[(co + j)*LP + r] = v[j];
      }
    }
    __syncthreads();

    // S = Q @ K^T
    f32x4 s[4] = {};
#pragma unroll
    for (int d0 = 0; d0 < 64; d0 += 32) {
      bf16x8 aq = *(const bf16x8*)&Qs[(wave*16 + l15)*LP + d0 + q4*8];
#pragma unroll
      for (int c = 0; c < 4; ++c) {
        bf16x8 bk = *(const bf16x8*)&Ks[(c*16 + l15)*LP + d0 + q4*8];
        s[c] = __builtin_amdgcn_mfma_f32_16x16x32_bf16(aq, bk, s[c], 0, 0, 0);
      }
    }
#pragma unroll
    for (int c = 0; c < 4; ++c)
#pragma unroll
      for (int i = 0; i < 4; ++i) s[c][i] *= scale;

    // online softmax per register-row i (row = wave*16 + q4*4 + i)
#pragma unroll
    for (int i = 0; i < 4; ++i) {
      float mx = -1e30f;
#pragma unroll
      for (int c = 0; c < 4; ++c) mx = fmaxf(mx, s[c][i]);
#pragma unroll
      for (int off = 1; off < 16; off <<= 1) mx = fmaxf(mx, __shfl_xor(mx, off, 64));
      float m_new = fmaxf(m_i[i], mx);
      float alpha = __expf(m_i[i] - m_new);
      float rowsum = 0.f;
#pragma unroll
      for (int c = 0; c < 4; ++c) {
        float p = __expf(s[c][i] - m_new);
        Ps[wave][(q4*4 + i)*LP + c*16 + l15] = (bf16)p;
        rowsum += p;
      }
#pragma unroll
      for (int off = 1; off < 16; off <<= 1) rowsum += __shfl_xor(rowsum, off, 64);
      l_i[i] = l_i[i]*alpha + rowsum;
      m_i[i] = m_new;
#pragma unroll
      for (int c = 0; c < 4; ++c) o_acc[c][i] *= alpha;
    }

    // O += P @ V
#pragma unroll
    for (int n0 = 0; n0 < 64; n0 += 32) {
      bf16x8 ap = *(const bf16x8*)&Ps[wave][l15*LP + n0 + q4*8];
#pragma unroll
      for (int c = 0; c < 4; ++c) {
        bf16x8 bv = *(const bf16x8*)&Vt[(c*16 + l15)*LP + n0 + q4*8];
        o_acc[c] = __builtin_amdgcn_mfma_f32_16x16x32_bf16(ap, bv, o_acc[c], 0, 0, 0);
      }
    }
  }

  bf16* obase = out + ((size_t)(b*S_ + qb*64 + wave*16))*D_ + h*64;
#pragma unroll
  for (int i = 0; i < 4; ++i) {
    float inv = 1.f / l_i[i];
#pragma unroll
    for (int c = 0; c < 4; ++c)
      obase[(size_t)(q4*4 + i)*D_ + c*16 + l15] = (bf16)(o_acc[c][i]*inv);
  }
}

// ---------------------------------------------------------------------------
// residual add + LayerNorm (fp32 stats), writes fp32 x, bf16 x, optional copy
// ---------------------------------------------------------------------------
__global__ __launch_bounds__(256) void add_ln_kernel(
    const float* __restrict__ xin, const float* __restrict__ yin,
    const float* __restrict__ w, const float* __restrict__ bta,
    float* __restrict__ xout, bf16* __restrict__ xbf,
    float* __restrict__ extra)
{
  const int row = blockIdx.x;
  const int tid = threadIdx.x;
  const size_t base = (size_t)row * D_;
  float v[4], sm = 0.f, ss = 0.f;
#pragma unroll
  for (int j = 0; j < 4; ++j) {
    int idx = tid + j*256;
    v[j] = xin[base + idx] + yin[base + idx];
    sm += v[j]; ss += v[j]*v[j];
  }
#pragma unroll
  for (int off = 1; off < 64; off <<= 1) {
    sm += __shfl_xor(sm, off, 64);
    ss += __shfl_xor(ss, off, 64);
  }
  __shared__ float red[8];
  const int wave = tid >> 6, lane = tid & 63;
  if (lane == 0) { red[wave] = sm; red[4 + wave] = ss; }
  __syncthreads();
  sm = red[0] + red[1] + red[2] + red[3];
  ss = red[4] + red[5] + red[6] + red[7];
  const float mean = sm * (1.f/D_);
  const float var  = ss * (1.f/D_) - mean*mean;
  const float rstd = rsqrtf(var + 1e-5f);
#pragma unroll
  for (int j = 0; j < 4; ++j) {
    int idx = tid + j*256;
    float o = (v[j] - mean)*rstd*w[idx] + bta[idx];
    xout[base + idx] = o;
    xbf[base + idx]  = (bf16)o;
    if (extra) extra[base + idx] = o;
  }
}

// ---------------------------------------------------------------------------
__global__ __launch_bounds__(256) void conv_kernel(
    const float4* __restrict__ src, bf16x4* __restrict__ dst, int n4)
{
  int i = blockIdx.x*blockDim.x + threadIdx.x;
  const int stride = gridDim.x*blockDim.x;
  for (; i < n4; i += stride) {
    float4 f = src[i];
    bf16x4 o;
    o[0] = (bf16)f.x; o[1] = (bf16)f.y; o[2] = (bf16)f.z; o[3] = (bf16)f.w;
    dst[i] = o;
  }
}

__global__ __launch_bounds__(256) void init_x_kernel(
    const float4* __restrict__ src, float4* __restrict__ xf,
    bf16x4* __restrict__ xb, int n4)
{
  int i = blockIdx.x*blockDim.x + threadIdx.x;
  const int stride = gridDim.x*blockDim.x;
  for (; i < n4; i += stride) {
    float4 f = src[i];
    xf[i] = f;
    bf16x4 o;
    o[0] = (bf16)f.x; o[1] = (bf16)f.y; o[2] = (bf16)f.z; o[3] = (bf16)f.w;
    xb[i] = o;
  }
}

// ---------------------------------------------------------------------------
extern "C" void kernel_launch(void* const* d_in, const int* in_sizes, int n_in,
                              void* d_out, int out_size, void* d_ws, size_t ws_size,
                              hipStream_t stream) {
  const float* x    = (const float*)d_in[0];
  const float* inw  = (const float*)d_in[1];
  const float* inb  = (const float*)d_in[2];
  const float* outw = (const float*)d_in[3];
  const float* outb = (const float*)d_in[4];
  const float* ln1w = (const float*)d_in[5];
  const float* ln1b = (const float*)d_in[6];
  const float* l1w  = (const float*)d_in[7];
  const float* l1b  = (const float*)d_in[8];
  const float* l2w  = (const float*)d_in[9];
  const float* l2b  = (const float*)d_in[10];
  const float* ln2w = (const float*)d_in[11];
  const float* ln2b = (const float*)d_in[12];

  char* ws = (char*)d_ws;
  size_t off = 0;
  auto take = [&](size_t bytes) {
    char* p = ws + off;
    off = (off + bytes + 255) & ~(size_t)255;
    return p;
  };
  bf16*  w_in_bf  = (bf16*) take((size_t)NL_*3*D_*D_*2);
  bf16*  w_out_bf = (bf16*) take((size_t)NL_*D_*D_*2);
  bf16*  w_l1_bf  = (bf16*) take((size_t)NL_*DFF_*D_*2);
  bf16*  w_l2_bf  = (bf16*) take((size_t)NL_*D_*DFF_*2);
  float* x_f      = (float*)take((size_t)M_*D_*4);
  bf16*  x_b      = (bf16*) take((size_t)M_*D_*2);
  bf16*  qkv_b    = (bf16*) take((size_t)M_*3*D_*2);
  bf16*  at_b     = (bf16*) take((size_t)M_*D_*2);
  bf16*  h_b      = (bf16*) take((size_t)M_*DFF_*2);
  float* tmp_f    = (float*)take((size_t)M_*D_*4);
  (void)ws_size; (void)in_sizes; (void)n_in;

  auto conv = [&](const float* s, bf16* d, size_t n) {
    int n4 = (int)(n >> 2);
    int grid = (n4 + 255) / 256; if (grid > 4096) grid = 4096;
    conv_kernel<<<grid, 256, 0, stream>>>((const float4*)s, (bf16x4*)d, n4);
  };
  conv(inw,  w_in_bf,  (size_t)NL_*3*D_*D_);
  conv(outw, w_out_bf, (size_t)NL_*D_*D_);
  conv(l1w,  w_l1_bf,  (size_t)NL_*DFF_*D_);
  conv(l2w,  w_l2_bf,  (size_t)NL_*D_*DFF_);
  init_x_kernel<<<4096, 256, 0, stream>>>((const float4*)x, (float4*)x_f,
                                          (bf16x4*)x_b, (int)((size_t)M_*D_ >> 2));

  for (int l = 0; l < NL_; ++l) {
    // qkv = x @ in_proj_w^T + b  [4096,3072]; grid 24x32=768, patch 12x8
    gemm_bt_kernel<0,1,128><<<768, 256, 0, stream>>>(
        x_b, w_in_bf + (size_t)l*3*D_*D_, inb + (size_t)l*3*D_,
        nullptr, qkv_b, 3*D_, D_, 24, 12, 8);
    // attention -> at_b [4096,1024] bf16
    attn_kernel<<<dim3(S_/64, B_*H_), 256, 0, stream>>>(qkv_b, at_b);
    // o = attn @ out_w^T + b -> tmp_f fp32; TN=64: grid 16x32=512, patch 8x8
    gemm_bt_kernel<0,0,64><<<512, 256, 0, stream>>>(
        at_b, w_out_bf + (size_t)l*D_*D_, outb + (size_t)l*D_,
        tmp_f, nullptr, D_, D_, 16, 8, 8);
    // x = LN(x + o)
    add_ln_kernel<<<M_, 256, 0, stream>>>(
        x_f, tmp_f, ln1w + (size_t)l*D_, ln1b + (size_t)l*D_,
        x_f, x_b, nullptr);
    // h = relu(x @ lin1^T + b) [4096,4096]; grid 32x32=1024, patch 16x8
    gemm_bt_kernel<1,1,128><<<1024, 256, 0, stream>>>(
        x_b, w_l1_bf + (size_t)l*DFF_*D_, l1b + (size_t)l*DFF_,
        nullptr, h_b, DFF_, D_, 32, 16, 8);
    // f = h @ lin2^T + b -> tmp_f; TN=64: grid 16x32=512, patch 8x8, K=4096
    gemm_bt_kernel<0,0,64><<<512, 256, 0, stream>>>(
        h_b, w_l2_bf + (size_t)l*D_*DFF_, l2b + (size_t)l*D_,
        tmp_f, nullptr, D_, DFF_, 16, 8, 8);
    // x = LN(x + f); last layer also writes d_out
    add_ln_kernel<<<M_, 256, 0, stream>>>(
        x_f, tmp_f, ln2w + (size_t)l*D_, ln2b + (size_t)l*D_,
        x_f, x_b, (l == NL_-1) ? (float*)d_out : nullptr);
  }
}

// Round 4
// 1382.026 us; speedup vs baseline: 1.3123x; 1.2640x over previous
//
#include <hip/hip_runtime.h>
#include <stdint.h>

typedef __bf16 bf16;
typedef __bf16 bf16x8 __attribute__((ext_vector_type(8)));
typedef __bf16 bf16x4 __attribute__((ext_vector_type(4)));
typedef float  f32x4  __attribute__((ext_vector_type(4)));

#define B_   4
#define S_   1024
#define D_   1024
#define H_   16
#define DH_  64
#define DFF_ 4096
#define NL_  4
#define M_   (B_*S_)   // 4096 rows of activations

// ---------------------------------------------------------------------------
// async global->LDS copy, 16B per lane. LDS dest is wave-uniform base; lane i
// lands at base + i*16 bytes (guide §5 caveat).
// ---------------------------------------------------------------------------
__device__ __forceinline__ void async_copy16(const void* g, void* l) {
  __builtin_amdgcn_global_load_lds(
      (const __attribute__((address_space(1))) char*)(uintptr_t)g,
      (__attribute__((address_space(3))) char*)(uintptr_t)l,
      16, 0, 0);
}

// ---------------------------------------------------------------------------
// GEMM (BT form): C[M,N] = A[M,K] @ W[N,K]^T + bias, optional relu.
// TM=TN=128, BK=64, 4 waves 2x2 over 64x64 quadrants, mfma_f32_16x16x32_bf16.
//
// Software pipeline (double-buffered LDS, 2 x 32KB):
//   stage(buf0); barrier;
//   for k: { stage(buf[k+1]); compute(buf[k]); barrier; }
// The vmcnt(0) drain at each barrier waits on loads issued BEFORE the whole
// compute phase -> exposed latency = max(0, load_latency - compute).
//
// Staging (coalesced + XOR swizzle): per issue, 8 rows x 128B. lane ->
// (r=lane>>3, c=lane&7); global chunk index = c ^ (row&7); LDS is plain
// row-major [row][64 el]. Each row is one contiguous 128B global segment.
// Fragment read for k-group g of row r reads chunk g ^ (r&7): bank
// enumeration gives 8 distinct 4-bank groups per 8-lane phase -> conflict-
// free (and round 2/3 measured 0 conflicts with the swizzle-free variant).
//
// XCD patch swizzle: L -> xcd = L&7, slot s = L>>3; each XCD owns a PN x PM
// patch of (bn,bm) tiles (grid == 8*PN*PM, Gn = gx/PN, Gn*(gy/PM) == 8).
// Verified round 3: FETCH 135 -> 49MB.
// ---------------------------------------------------------------------------
template<int RELU, int OUT_BF16>
__global__ __launch_bounds__(256) void gemm_bt_kernel(
    const bf16* __restrict__ A,     // [M,K] row-major bf16
    const bf16* __restrict__ W,     // [N,K] row-major bf16
    const float* __restrict__ bias, // [N]
    float* __restrict__ Cf,         // used if !OUT_BF16
    bf16*  __restrict__ Cb,         // used if OUT_BF16
    int N, int K, int gx, int PN, int PM)
{
  __shared__ bf16 As[2][128*64];    // 2 x 16KB
  __shared__ bf16 Bs[2][128*64];    // 2 x 16KB

  const int tid  = threadIdx.x;
  const int wave = tid >> 6;
  const int lane = tid & 63;
  const int wr = wave >> 1, wc = wave & 1;
  const int q4  = lane >> 4;
  const int l15 = lane & 15;

  // XCD-patch swizzle
  const int L   = blockIdx.x;
  const int xcd = L & 7;
  const int s   = L >> 3;
  const int Gn  = gx / PN;
  const int bn = ((xcd % Gn)*PN + (s % PN)) << 7;
  const int bm = ((xcd / Gn)*PM + (s / PN)) << 7;

  // staging pointers: wave w covers rows w*32..w*32+31, 4 issues of 8 rows
  const int r_loc = lane >> 3, c8 = lane & 7;
  const bf16* agp[4]; const bf16* wgp[4];
  int ldsb[4];
#pragma unroll
  for (int j = 0; j < 4; ++j) {
    const int rr = wave*32 + j*8 + r_loc;          // row within tile
    const int ko = ((c8 ^ (rr & 7)) << 3);         // swizzled k-chunk offset
    agp[j] = A + (size_t)(bm + rr)*K + ko;
    wgp[j] = W + (size_t)(bn + rr)*K + ko;
    ldsb[j] = (wave*32 + j*8) * 64;                // wave-uniform LDS base
  }

  auto stage = [&]() {
    // buf alternation handled by caller passing base pointers
  };
  (void)stage;

  f32x4 acc[4][4] = {};

  const int steps = K >> 6;

#define STAGE(BUF)                                                   \
  {                                                                  \
    _Pragma("unroll")                                                \
    for (int j = 0; j < 4; ++j) {                                    \
      async_copy16(agp[j], &As[BUF][ldsb[j]]);                       \
      async_copy16(wgp[j], &Bs[BUF][ldsb[j]]);                       \
      agp[j] += 64; wgp[j] += 64;                                    \
    }                                                                \
  }

#define COMPUTE(BUF)                                                 \
  {                                                                  \
    _Pragma("unroll")                                                \
    for (int kk = 0; kk < 2; ++kk) {                                 \
      const int ch = (((kk << 2) | q4) ^ (l15 & 7)) << 3;            \
      bf16x8 af[4], bfr[4];                                          \
      _Pragma("unroll")                                              \
      for (int rf = 0; rf < 4; ++rf)                                 \
        af[rf] = *(const bf16x8*)&As[BUF][(wr*64 + rf*16 + l15)*64 + ch]; \
      _Pragma("unroll")                                              \
      for (int cf = 0; cf < 4; ++cf)                                 \
        bfr[cf] = *(const bf16x8*)&Bs[BUF][(wc*64 + cf*16 + l15)*64 + ch]; \
      _Pragma("unroll")                                              \
      for (int rf = 0; rf < 4; ++rf)                                 \
        _Pragma("unroll")                                            \
        for (int cf = 0; cf < 4; ++cf)                               \
          acc[rf][cf] = __builtin_amdgcn_mfma_f32_16x16x32_bf16(     \
              af[rf], bfr[cf], acc[rf][cf], 0, 0, 0);                \
    }                                                                \
  }

  STAGE(0)
  __syncthreads();           // drain buf0
  for (int k = 0; k < steps; ++k) {
    const int cur = k & 1, nxt = cur ^ 1;
    if (k + 1 < steps) {
      if (nxt) STAGE(1) else STAGE(0)
    }
    if (cur) COMPUTE(1) else COMPUTE(0)
    __syncthreads();         // drains next-buf loads; frees cur for restage
  }
#undef STAGE
#undef COMPUTE

  // epilogue: C/D layout col=lane&15, row=quad*4+reg (m89-verified)
#pragma unroll
  for (int r = 0; r < 4; ++r) {
    const int row0 = bm + wr*64 + r*16 + q4*4;
#pragma unroll
    for (int c = 0; c < 4; ++c) {
      const int col = bn + wc*64 + c*16 + l15;
      const float bv = bias[col];
#pragma unroll
      for (int i = 0; i < 4; ++i) {
        float v = acc[r][c][i] + bv;
        if (RELU) v = fmaxf(v, 0.f);
        if (OUT_BF16) Cb[(size_t)(row0 + i)*N + col] = (bf16)v;
        else          Cf[(size_t)(row0 + i)*N + col] = v;
      }
    }
  }
}

// ---------------------------------------------------------------------------
// Flash-style block-causal attention. One workgroup per (qblock, b*H+h).
// BLK==64 == tile, so no intra-tile masking.
// ---------------------------------------------------------------------------
#define LP 72
__global__ __launch_bounds__(256) void attn_kernel(
    const bf16* __restrict__ qkv,  // [M, 3*D] rows b*S+s; Q|K|V col blocks
    bf16* __restrict__ out)        // [M, D]
{
  const int qb  = blockIdx.x;          // 0..15
  const int bh  = blockIdx.y;          // 0..63
  const int b   = bh >> 4, h = bh & 15;
  const int tid = threadIdx.x;
  const int wave = tid >> 6, lane = tid & 63;
  const int q4 = lane >> 4, l15 = lane & 15;

  __shared__ bf16 Qs[64*LP];
  __shared__ bf16 Ks[64*LP];
  __shared__ bf16 Vt[64*LP];       // transposed: Vt[d][n]
  __shared__ bf16 Ps[4][16*LP];    // per-wave P strip (C-layout -> A-layout)

  const size_t RS = 3*(size_t)D_;
  const bf16* qbase = qkv + ((size_t)(b*S_ + qb*64))*RS + h*64;

  {
    int cidx = tid;
#pragma unroll
    for (int it = 0; it < 2; ++it, cidx += 256) {
      int r = cidx >> 3, co = (cidx & 7)*8;
      *(bf16x8*)&Qs[r*LP + co] = *(const bf16x8*)&qbase[(size_t)r*RS + co];
    }
  }

  f32x4 o_acc[4] = {};
  float m_i[4], l_i[4];
#pragma unroll
  for (int i = 0; i < 4; ++i) { m_i[i] = -1e30f; l_i[i] = 0.f; }
  const float scale = 0.125f;   // 1/sqrt(64)

  for (int kt = 0; kt <= qb; ++kt) {
    __syncthreads();
    const bf16* kbase = qkv + ((size_t)(b*S_ + kt*64))*RS + D_   + h*64;
    const bf16* vbase = qkv + ((size_t)(b*S_ + kt*64))*RS + 2*D_ + h*64;
    {
      int cidx = tid;
#pragma unroll
      for (int it = 0; it < 2; ++it, cidx += 256) {
        int r = cidx >> 3, co = (cidx & 7)*8;
        *(bf16x8*)&Ks[r*LP + co] = *(const bf16x8*)&kbase[(size_t)r*RS + co];
        bf16x8 v = *(const bf16x8*)&vbase[(size_t)r*RS + co];
#pragma unroll
        for (int j = 0; j < 8; ++j) Vt[(co + j)*LP + r] = v[j];
      }
    }
    __syncthreads();

    // S = Q @ K^T
    f32x4 s[4] = {};
#pragma unroll
    for (int d0 = 0; d0 < 64; d0 += 32) {
      bf16x8 aq = *(const bf16x8*)&Qs[(wave*16 + l15)*LP + d0 + q4*8];
#pragma unroll
      for (int c = 0; c < 4; ++c) {
        bf16x8 bk = *(const bf16x8*)&Ks[(c*16 + l15)*LP + d0 + q4*8];
        s[c] = __builtin_amdgcn_mfma_f32_16x16x32_bf16(aq, bk, s[c], 0, 0, 0);
      }
    }
#pragma unroll
    for (int c = 0; c < 4; ++c)
#pragma unroll
      for (int i = 0; i < 4; ++i) s[c][i] *= scale;

    // online softmax per register-row i (row = wave*16 + q4*4 + i)
#pragma unroll
    for (int i = 0; i < 4; ++i) {
      float mx = -1e30f;
#pragma unroll
      for (int c = 0; c < 4; ++c) mx = fmaxf(mx, s[c][i]);
#pragma unroll
      for (int off = 1; off < 16; off <<= 1) mx = fmaxf(mx, __shfl_xor(mx, off, 64));
      float m_new = fmaxf(m_i[i], mx);
      float alpha = __expf(m_i[i] - m_new);
      float rowsum = 0.f;
#pragma unroll
      for (int c = 0; c < 4; ++c) {
        float p = __expf(s[c][i] - m_new);
        Ps[wave][(q4*4 + i)*LP + c*16 + l15] = (bf16)p;
        rowsum += p;
      }
#pragma unroll
      for (int off = 1; off < 16; off <<= 1) rowsum += __shfl_xor(rowsum, off, 64);
      l_i[i] = l_i[i]*alpha + rowsum;
      m_i[i] = m_new;
#pragma unroll
      for (int c = 0; c < 4; ++c) o_acc[c][i] *= alpha;
    }

    // O += P @ V
#pragma unroll
    for (int n0 = 0; n0 < 64; n0 += 32) {
      bf16x8 ap = *(const bf16x8*)&Ps[wave][l15*LP + n0 + q4*8];
#pragma unroll
      for (int c = 0; c < 4; ++c) {
        bf16x8 bv = *(const bf16x8*)&Vt[(c*16 + l15)*LP + n0 + q4*8];
        o_acc[c] = __builtin_amdgcn_mfma_f32_16x16x32_bf16(ap, bv, o_acc[c], 0, 0, 0);
      }
    }
  }

  bf16* obase = out + ((size_t)(b*S_ + qb*64 + wave*16))*D_ + h*64;
#pragma unroll
  for (int i = 0; i < 4; ++i) {
    float inv = 1.f / l_i[i];
#pragma unroll
    for (int c = 0; c < 4; ++c)
      obase[(size_t)(q4*4 + i)*D_ + c*16 + l15] = (bf16)(o_acc[c][i]*inv);
  }
}

// ---------------------------------------------------------------------------
// residual add + LayerNorm (fp32 stats), writes fp32 x, bf16 x, optional copy
// ---------------------------------------------------------------------------
__global__ __launch_bounds__(256) void add_ln_kernel(
    const float* __restrict__ xin, const float* __restrict__ yin,
    const float* __restrict__ w, const float* __restrict__ bta,
    float* __restrict__ xout, bf16* __restrict__ xbf,
    float* __restrict__ extra)
{
  const int row = blockIdx.x;
  const int tid = threadIdx.x;
  const size_t base = (size_t)row * D_;
  float v[4], sm = 0.f, ss = 0.f;
#pragma unroll
  for (int j = 0; j < 4; ++j) {
    int idx = tid + j*256;
    v[j] = xin[base + idx] + yin[base + idx];
    sm += v[j]; ss += v[j]*v[j];
  }
#pragma unroll
  for (int off = 1; off < 64; off <<= 1) {
    sm += __shfl_xor(sm, off, 64);
    ss += __shfl_xor(ss, off, 64);
  }
  __shared__ float red[8];
  const int wave = tid >> 6, lane = tid & 63;
  if (lane == 0) { red[wave] = sm; red[4 + wave] = ss; }
  __syncthreads();
  sm = red[0] + red[1] + red[2] + red[3];
  ss = red[4] + red[5] + red[6] + red[7];
  const float mean = sm * (1.f/D_);
  const float var  = ss * (1.f/D_) - mean*mean;
  const float rstd = rsqrtf(var + 1e-5f);
#pragma unroll
  for (int j = 0; j < 4; ++j) {
    int idx = tid + j*256;
    float o = (v[j] - mean)*rstd*w[idx] + bta[idx];
    xout[base + idx] = o;
    xbf[base + idx]  = (bf16)o;
    if (extra) extra[base + idx] = o;
  }
}

// ---------------------------------------------------------------------------
__global__ __launch_bounds__(256) void conv_kernel(
    const float4* __restrict__ src, bf16x4* __restrict__ dst, int n4)
{
  int i = blockIdx.x*blockDim.x + threadIdx.x;
  const int stride = gridDim.x*blockDim.x;
  for (; i < n4; i += stride) {
    float4 f = src[i];
    bf16x4 o;
    o[0] = (bf16)f.x; o[1] = (bf16)f.y; o[2] = (bf16)f.z; o[3] = (bf16)f.w;
    dst[i] = o;
  }
}

__global__ __launch_bounds__(256) void init_x_kernel(
    const float4* __restrict__ src, float4* __restrict__ xf,
    bf16x4* __restrict__ xb, int n4)
{
  int i = blockIdx.x*blockDim.x + threadIdx.x;
  const int stride = gridDim.x*blockDim.x;
  for (; i < n4; i += stride) {
    float4 f = src[i];
    xf[i] = f;
    bf16x4 o;
    o[0] = (bf16)f.x; o[1] = (bf16)f.y; o[2] = (bf16)f.z; o[3] = (bf16)f.w;
    xb[i] = o;
  }
}

// ---------------------------------------------------------------------------
extern "C" void kernel_launch(void* const* d_in, const int* in_sizes, int n_in,
                              void* d_out, int out_size, void* d_ws, size_t ws_size,
                              hipStream_t stream) {
  const float* x    = (const float*)d_in[0];
  const float* inw  = (const float*)d_in[1];
  const float* inb  = (const float*)d_in[2];
  const float* outw = (const float*)d_in[3];
  const float* outb = (const float*)d_in[4];
  const float* ln1w = (const float*)d_in[5];
  const float* ln1b = (const float*)d_in[6];
  const float* l1w  = (const float*)d_in[7];
  const float* l1b  = (const float*)d_in[8];
  const float* l2w  = (const float*)d_in[9];
  const float* l2b  = (const float*)d_in[10];
  const float* ln2w = (const float*)d_in[11];
  const float* ln2b = (const float*)d_in[12];

  char* ws = (char*)d_ws;
  size_t off = 0;
  auto take = [&](size_t bytes) {
    char* p = ws + off;
    off = (off + bytes + 255) & ~(size_t)255;
    return p;
  };
  bf16*  w_in_bf  = (bf16*) take((size_t)NL_*3*D_*D_*2);
  bf16*  w_out_bf = (bf16*) take((size_t)NL_*D_*D_*2);
  bf16*  w_l1_bf  = (bf16*) take((size_t)NL_*DFF_*D_*2);
  bf16*  w_l2_bf  = (bf16*) take((size_t)NL_*D_*DFF_*2);
  float* x_f      = (float*)take((size_t)M_*D_*4);
  bf16*  x_b      = (bf16*) take((size_t)M_*D_*2);
  bf16*  qkv_b    = (bf16*) take((size_t)M_*3*D_*2);
  bf16*  at_b     = (bf16*) take((size_t)M_*D_*2);
  bf16*  h_b      = (bf16*) take((size_t)M_*DFF_*2);
  float* tmp_f    = (float*)take((size_t)M_*D_*4);
  (void)ws_size; (void)in_sizes; (void)n_in;

  auto conv = [&](const float* s, bf16* d, size_t n) {
    int n4 = (int)(n >> 2);
    int grid = (n4 + 255) / 256; if (grid > 4096) grid = 4096;
    conv_kernel<<<grid, 256, 0, stream>>>((const float4*)s, (bf16x4*)d, n4);
  };
  conv(inw,  w_in_bf,  (size_t)NL_*3*D_*D_);
  conv(outw, w_out_bf, (size_t)NL_*D_*D_);
  conv(l1w,  w_l1_bf,  (size_t)NL_*DFF_*D_);
  conv(l2w,  w_l2_bf,  (size_t)NL_*D_*DFF_);
  init_x_kernel<<<4096, 256, 0, stream>>>((const float4*)x, (float4*)x_f,
                                          (bf16x4*)x_b, (int)((size_t)M_*D_ >> 2));

  for (int l = 0; l < NL_; ++l) {
    // qkv = x @ in_proj_w^T + b  [4096,3072]; grid 24x32=768, patch 12x8
    gemm_bt_kernel<0,1><<<768, 256, 0, stream>>>(
        x_b, w_in_bf + (size_t)l*3*D_*D_, inb + (size_t)l*3*D_,
        nullptr, qkv_b, 3*D_, D_, 24, 12, 8);
    // attention -> at_b [4096,1024] bf16
    attn_kernel<<<dim3(S_/64, B_*H_), 256, 0, stream>>>(qkv_b, at_b);
    // o = attn @ out_w^T + b -> tmp_f fp32; grid 8x32=256, patch 4x8
    gemm_bt_kernel<0,0><<<256, 256, 0, stream>>>(
        at_b, w_out_bf + (size_t)l*D_*D_, outb + (size_t)l*D_,
        tmp_f, nullptr, D_, D_, 8, 4, 8);
    // x = LN(x + o)
    add_ln_kernel<<<M_, 256, 0, stream>>>(
        x_f, tmp_f, ln1w + (size_t)l*D_, ln1b + (size_t)l*D_,
        x_f, x_b, nullptr);
    // h = relu(x @ lin1^T + b) [4096,4096]; grid 32x32=1024, patch 16x8
    gemm_bt_kernel<1,1><<<1024, 256, 0, stream>>>(
        x_b, w_l1_bf + (size_t)l*DFF_*D_, l1b + (size_t)l*DFF_,
        nullptr, h_b, DFF_, D_, 32, 16, 8);
    // f = h @ lin2^T + b -> tmp_f; grid 8x32=256, patch 4x8, K=4096
    gemm_bt_kernel<0,0><<<256, 256, 0, stream>>>(
        h_b, w_l2_bf + (size_t)l*D_*DFF_, l2b + (size_t)l*D_,
        tmp_f, nullptr, D_, DFF_, 8, 4, 8);
    // x = LN(x + f); last layer also writes d_out
    add_ln_kernel<<<M_, 256, 0, stream>>>(
        x_f, tmp_f, ln2w + (size_t)l*D_, ln2b + (size_t)l*D_,
        x_f, x_b, (l == NL_-1) ? (float*)d_out : nullptr);
  }
}

// Round 5
// 1223.983 us; speedup vs baseline: 1.4817x; 1.1291x over previous
//
#include <hip/hip_runtime.h>
#include <stdint.h>

typedef __bf16 bf16;
typedef __bf16 bf16x8 __attribute__((ext_vector_type(8)));
typedef __bf16 bf16x4 __attribute__((ext_vector_type(4)));
typedef float  f32x4  __attribute__((ext_vector_type(4)));

#define B_   4
#define S_   1024
#define D_   1024
#define H_   16
#define DH_  64
#define DFF_ 4096
#define NL_  4
#define M_   (B_*S_)   // 4096 rows of activations

// ---------------------------------------------------------------------------
// async global->LDS copy, 16B per lane. LDS dest is wave-uniform base; lane i
// lands at base + i*16 bytes (guide §5 caveat).
// ---------------------------------------------------------------------------
__device__ __forceinline__ void async_copy16(const void* g, void* l) {
  __builtin_amdgcn_global_load_lds(
      (const __attribute__((address_space(1))) char*)(uintptr_t)g,
      (__attribute__((address_space(3))) char*)(uintptr_t)l,
      16, 0, 0);
}

// ---------------------------------------------------------------------------
// GEMM (BT form): C[M,N] = A[M,K] @ W[N,K]^T + bias, optional relu.
// TM=TN=128, BK=64, 4 waves 2x2 over 64x64 quadrants, mfma_f32_16x16x32_bf16.
// Double-buffered LDS pipeline + XOR-swizzled coalesced staging (round 4:
// conflict-free, FETCH == footprint, 1382us total).
// QKV==1: tiles with bn >= 2048 are the V third of the projection; write them
// TRANSPOSED per (b,h) into VtOut[b][h][64][S] (bf16x4 stores along s) so the
// attention kernel needs no in-LDS transpose.
// ---------------------------------------------------------------------------
template<int RELU, int OUT_BF16, int QKV>
__global__ __launch_bounds__(256) void gemm_bt_kernel(
    const bf16* __restrict__ A,     // [M,K] row-major bf16
    const bf16* __restrict__ W,     // [N,K] row-major bf16
    const float* __restrict__ bias, // [N]
    float* __restrict__ Cf,         // used if !OUT_BF16
    bf16*  __restrict__ Cb,         // used if OUT_BF16
    bf16*  __restrict__ VtOut,      // used if QKV
    int N, int K, int gx, int PN, int PM)
{
  __shared__ bf16 As[2][128*64];    // 2 x 16KB
  __shared__ bf16 Bs[2][128*64];    // 2 x 16KB

  const int tid  = threadIdx.x;
  const int wave = tid >> 6;
  const int lane = tid & 63;
  const int wr = wave >> 1, wc = wave & 1;
  const int q4  = lane >> 4;
  const int l15 = lane & 15;

  // XCD-patch swizzle (round 3: FETCH 135 -> 49MB)
  const int L   = blockIdx.x;
  const int xcd = L & 7;
  const int s   = L >> 3;
  const int Gn  = gx / PN;
  const int bn = ((xcd % Gn)*PN + (s % PN)) << 7;
  const int bm = ((xcd / Gn)*PM + (s / PN)) << 7;

  // staging: wave w covers rows w*32..w*32+31, 4 issues of 8 rows x 128B
  const int r_loc = lane >> 3, c8 = lane & 7;
  const bf16* agp[4]; const bf16* wgp[4];
  int ldsb[4];
#pragma unroll
  for (int j = 0; j < 4; ++j) {
    const int rr = wave*32 + j*8 + r_loc;
    const int ko = ((c8 ^ (rr & 7)) << 3);         // XOR-swizzled k-chunk
    agp[j] = A + (size_t)(bm + rr)*K + ko;
    wgp[j] = W + (size_t)(bn + rr)*K + ko;
    ldsb[j] = (wave*32 + j*8) * 64;
  }

  f32x4 acc[4][4] = {};
  const int steps = K >> 6;

#define STAGE(BUF)                                                   \
  {                                                                  \
    _Pragma("unroll")                                                \
    for (int j = 0; j < 4; ++j) {                                    \
      async_copy16(agp[j], &As[BUF][ldsb[j]]);                       \
      async_copy16(wgp[j], &Bs[BUF][ldsb[j]]);                       \
      agp[j] += 64; wgp[j] += 64;                                    \
    }                                                                \
  }

#define COMPUTE(BUF)                                                 \
  {                                                                  \
    _Pragma("unroll")                                                \
    for (int kk = 0; kk < 2; ++kk) {                                 \
      const int ch = (((kk << 2) | q4) ^ (l15 & 7)) << 3;            \
      bf16x8 af[4], bfr[4];                                          \
      _Pragma("unroll")                                              \
      for (int rf = 0; rf < 4; ++rf)                                 \
        af[rf] = *(const bf16x8*)&As[BUF][(wr*64 + rf*16 + l15)*64 + ch]; \
      _Pragma("unroll")                                              \
      for (int cf = 0; cf < 4; ++cf)                                 \
        bfr[cf] = *(const bf16x8*)&Bs[BUF][(wc*64 + cf*16 + l15)*64 + ch]; \
      _Pragma("unroll")                                              \
      for (int rf = 0; rf < 4; ++rf)                                 \
        _Pragma("unroll")                                            \
        for (int cf = 0; cf < 4; ++cf)                               \
          acc[rf][cf] = __builtin_amdgcn_mfma_f32_16x16x32_bf16(     \
              af[rf], bfr[cf], acc[rf][cf], 0, 0, 0);                \
    }                                                                \
  }

  STAGE(0)
  __syncthreads();
  for (int k = 0; k < steps; ++k) {
    const int cur = k & 1, nxt = cur ^ 1;
    if (k + 1 < steps) {
      if (nxt) STAGE(1) else STAGE(0)
    }
    if (cur) COMPUTE(1) else COMPUTE(0)
    __syncthreads();
  }
#undef STAGE
#undef COMPUTE

  // epilogue: C/D layout col=lane&15, row=quad*4+reg (m89-verified)
  if (QKV && bn >= 2*D_) {
    // V third -> transposed Vt[b][h][64][S]; rows i are consecutive s
#pragma unroll
    for (int r = 0; r < 4; ++r) {
      const int row0 = bm + wr*64 + r*16 + q4*4;
      const int bidx = row0 >> 10, s0 = row0 & 1023;
#pragma unroll
      for (int c = 0; c < 4; ++c) {
        const int col  = bn + wc*64 + c*16 + l15;
        const int dcol = col - 2*D_;
        const int hh = dcol >> 6, dd = dcol & 63;
        const float bv = bias[col];
        bf16x4 pk;
#pragma unroll
        for (int i = 0; i < 4; ++i) pk[i] = (bf16)(acc[r][c][i] + bv);
        *(bf16x4*)&VtOut[((size_t)((bidx*H_ + hh)*64 + dd))*S_ + s0] = pk;
      }
    }
  } else {
#pragma unroll
    for (int r = 0; r < 4; ++r) {
      const int row0 = bm + wr*64 + r*16 + q4*4;
#pragma unroll
      for (int c = 0; c < 4; ++c) {
        const int col = bn + wc*64 + c*16 + l15;
        const float bv = bias[col];
#pragma unroll
        for (int i = 0; i < 4; ++i) {
          float v = acc[r][c][i] + bv;
          if (RELU) v = fmaxf(v, 0.f);
          if (OUT_BF16) Cb[(size_t)(row0 + i)*N + col] = (bf16)v;
          else          Cf[(size_t)(row0 + i)*N + col] = v;
        }
      }
    }
  }
}

// ---------------------------------------------------------------------------
// Flash-style block-causal attention, restructured (round 5):
//  - V arrives pre-transposed (Vt[b][h][64][S]) from the QKV GEMM epilogue:
//    no in-kernel transpose, no scalar LDS writes for V.
//  - Q/K/Vt staged via global_load_lds w=16 with XOR swizzle (conflict-free
//    b128 fragment reads, same scheme as the GEMM).
//  - K/V double-buffered: one barrier per K-tile, staging overlaps compute.
//  - 1D grid with XCD swizzle: all 16 qb of one (b,h) on one XCD (KV L2 reuse).
// BLK==64 == tile, so no intra-tile masking.
// ---------------------------------------------------------------------------
#define LP 72
__global__ __launch_bounds__(256) void attn_kernel(
    const bf16* __restrict__ qkv,  // [M][3072]: Q at +0, K at +1024 (V unused)
    const bf16* __restrict__ vt,   // [B*H][64][S]
    bf16* __restrict__ out)        // [M][D]
{
  const int L    = blockIdx.x;           // 0..1023
  const int xcd  = L & 7, slot = L >> 3; // slot 0..127
  const int qb   = slot & 15;
  const int bh   = xcd*8 + (slot >> 4);  // 8 (b,h) pairs per XCD
  const int b    = bh >> 4, h = bh & 15;
  const int tid  = threadIdx.x;
  const int wave = tid >> 6, lane = tid & 63;
  const int q4 = lane >> 4, l15 = lane & 15;
  const int r_loc = lane >> 3, c8 = lane & 7;

  __shared__ bf16 Qs[64*64];
  __shared__ bf16 Ks[2][64*64];
  __shared__ bf16 Vs[2][64*64];    // Vt tile: rows = d, cols = s-chunk
  __shared__ bf16 Ps[4][16*LP];    // per-wave P strip (C-layout -> A-layout)

  const size_t RS = 3*(size_t)D_;
  const bf16* qg = qkv + (size_t)(b*S_ + qb*64)*RS + h*64;
  const bf16* kg = qkv + (size_t)(b*S_)*RS + D_ + h*64;   // + row*RS
  const bf16* vg = vt + (size_t)bh*64*S_;                 // + d*S_ + s

  // stage Q (2 issues/wave of 8 rows x 128B, XOR swizzle)
#pragma unroll
  for (int j = 0; j < 2; ++j) {
    const int rr = wave*16 + j*8 + r_loc;
    const int ko = ((c8 ^ (rr & 7)) << 3);
    async_copy16(qg + (size_t)rr*RS + ko, &Qs[(wave*16 + j*8)*64]);
  }

#define STAGE_KV(KT, BUF)                                              \
  {                                                                    \
    _Pragma("unroll")                                                  \
    for (int j = 0; j < 2; ++j) {                                      \
      const int rr = wave*16 + j*8 + r_loc;                            \
      const int ko = ((c8 ^ (rr & 7)) << 3);                           \
      async_copy16(kg + (size_t)((KT)*64 + rr)*RS + ko,                \
                   &Ks[BUF][(wave*16 + j*8)*64]);                      \
      async_copy16(vg + (size_t)rr*S_ + (KT)*64 + ko,                  \
                   &Vs[BUF][(wave*16 + j*8)*64]);                      \
    }                                                                  \
  }

  f32x4 o_acc[4] = {};
  float m_i[4], l_i[4];
#pragma unroll
  for (int i = 0; i < 4; ++i) { m_i[i] = -1e30f; l_i[i] = 0.f; }
  const float scale = 0.125f;   // 1/sqrt(64)

  STAGE_KV(0, 0)
  __syncthreads();             // drains Q + first K/V

  for (int kt = 0; kt <= qb; ++kt) {
    const int cur = kt & 1;
    if (kt < qb) {
      if (cur) STAGE_KV(kt+1, 0) else STAGE_KV(kt+1, 1)
    }

    // S = Q @ K^T  (wave covers query rows wave*16..+15)
    f32x4 sc[4] = {};
#pragma unroll
    for (int kk = 0; kk < 2; ++kk) {
      const int go = ((((kk << 2) | q4)) ^ (l15 & 7)) << 3;
      bf16x8 aq = *(const bf16x8*)&Qs[(wave*16 + l15)*64 + go];
#pragma unroll
      for (int c = 0; c < 4; ++c) {
        bf16x8 bk = *(const bf16x8*)&Ks[cur][(c*16 + l15)*64 + go];
        sc[c] = __builtin_amdgcn_mfma_f32_16x16x32_bf16(aq, bk, sc[c], 0, 0, 0);
      }
    }
#pragma unroll
    for (int c = 0; c < 4; ++c)
#pragma unroll
      for (int i = 0; i < 4; ++i) sc[c][i] *= scale;

    // online softmax per register-row i (row = wave*16 + q4*4 + i)
#pragma unroll
    for (int i = 0; i < 4; ++i) {
      float mx = -1e30f;
#pragma unroll
      for (int c = 0; c < 4; ++c) mx = fmaxf(mx, sc[c][i]);
#pragma unroll
      for (int off = 1; off < 16; off <<= 1) mx = fmaxf(mx, __shfl_xor(mx, off, 64));
      float m_new = fmaxf(m_i[i], mx);
      float alpha = __expf(m_i[i] - m_new);
      float rowsum = 0.f;
#pragma unroll
      for (int c = 0; c < 4; ++c) {
        float p = __expf(sc[c][i] - m_new);
        Ps[wave][(q4*4 + i)*LP + c*16 + l15] = (bf16)p;
        rowsum += p;
      }
#pragma unroll
      for (int off = 1; off < 16; off <<= 1) rowsum += __shfl_xor(rowsum, off, 64);
      l_i[i] = l_i[i]*alpha + rowsum;
      m_i[i] = m_new;
#pragma unroll
      for (int c = 0; c < 4; ++c) o_acc[c][i] *= alpha;
    }

    // O += P @ V  (Ps wave-private; Vs rows are d, conflict-free via swizzle)
#pragma unroll
    for (int kk = 0; kk < 2; ++kk) {
      bf16x8 ap = *(const bf16x8*)&Ps[wave][l15*LP + kk*32 + q4*8];
#pragma unroll
      for (int c = 0; c < 4; ++c) {
        const int go = ((((kk << 2) | q4)) ^ (l15 & 7)) << 3;
        bf16x8 bv = *(const bf16x8*)&Vs[cur][(c*16 + l15)*64 + go];
        o_acc[c] = __builtin_amdgcn_mfma_f32_16x16x32_bf16(ap, bv, o_acc[c], 0, 0, 0);
      }
    }
    __syncthreads();   // drains next K/V loads; frees cur for restage
  }
#undef STAGE_KV

  bf16* obase = out + ((size_t)(b*S_ + qb*64 + wave*16))*D_ + h*64;
#pragma unroll
  for (int i = 0; i < 4; ++i) {
    float inv = 1.f / l_i[i];
#pragma unroll
    for (int c = 0; c < 4; ++c)
      obase[(size_t)(q4*4 + i)*D_ + c*16 + l15] = (bf16)(o_acc[c][i]*inv);
  }
}

// ---------------------------------------------------------------------------
// residual add + LayerNorm (fp32 stats), writes fp32 x, bf16 x, optional copy
// ---------------------------------------------------------------------------
__global__ __launch_bounds__(256) void add_ln_kernel(
    const float* __restrict__ xin, const float* __restrict__ yin,
    const float* __restrict__ w, const float* __restrict__ bta,
    float* __restrict__ xout, bf16* __restrict__ xbf,
    float* __restrict__ extra)
{
  const int row = blockIdx.x;
  const int tid = threadIdx.x;
  const size_t base = (size_t)row * D_;
  float v[4], sm = 0.f, ss = 0.f;
#pragma unroll
  for (int j = 0; j < 4; ++j) {
    int idx = tid + j*256;
    v[j] = xin[base + idx] + yin[base + idx];
    sm += v[j]; ss += v[j]*v[j];
  }
#pragma unroll
  for (int off = 1; off < 64; off <<= 1) {
    sm += __shfl_xor(sm, off, 64);
    ss += __shfl_xor(ss, off, 64);
  }
  __shared__ float red[8];
  const int wave = tid >> 6, lane = tid & 63;
  if (lane == 0) { red[wave] = sm; red[4 + wave] = ss; }
  __syncthreads();
  sm = red[0] + red[1] + red[2] + red[3];
  ss = red[4] + red[5] + red[6] + red[7];
  const float mean = sm * (1.f/D_);
  const float var  = ss * (1.f/D_) - mean*mean;
  const float rstd = rsqrtf(var + 1e-5f);
#pragma unroll
  for (int j = 0; j < 4; ++j) {
    int idx = tid + j*256;
    float o = (v[j] - mean)*rstd*w[idx] + bta[idx];
    xout[base + idx] = o;
    xbf[base + idx]  = (bf16)o;
    if (extra) extra[base + idx] = o;
  }
}

// ---------------------------------------------------------------------------
__global__ __launch_bounds__(256) void conv_kernel(
    const float4* __restrict__ src, bf16x4* __restrict__ dst, int n4)
{
  int i = blockIdx.x*blockDim.x + threadIdx.x;
  const int stride = gridDim.x*blockDim.x;
  for (; i < n4; i += stride) {
    float4 f = src[i];
    bf16x4 o;
    o[0] = (bf16)f.x; o[1] = (bf16)f.y; o[2] = (bf16)f.z; o[3] = (bf16)f.w;
    dst[i] = o;
  }
}

__global__ __launch_bounds__(256) void init_x_kernel(
    const float4* __restrict__ src, float4* __restrict__ xf,
    bf16x4* __restrict__ xb, int n4)
{
  int i = blockIdx.x*blockDim.x + threadIdx.x;
  const int stride = gridDim.x*blockDim.x;
  for (; i < n4; i += stride) {
    float4 f = src[i];
    xf[i] = f;
    bf16x4 o;
    o[0] = (bf16)f.x; o[1] = (bf16)f.y; o[2] = (bf16)f.z; o[3] = (bf16)f.w;
    xb[i] = o;
  }
}

// ---------------------------------------------------------------------------
extern "C" void kernel_launch(void* const* d_in, const int* in_sizes, int n_in,
                              void* d_out, int out_size, void* d_ws, size_t ws_size,
                              hipStream_t stream) {
  const float* x    = (const float*)d_in[0];
  const float* inw  = (const float*)d_in[1];
  const float* inb  = (const float*)d_in[2];
  const float* outw = (const float*)d_in[3];
  const float* outb = (const float*)d_in[4];
  const float* ln1w = (const float*)d_in[5];
  const float* ln1b = (const float*)d_in[6];
  const float* l1w  = (const float*)d_in[7];
  const float* l1b  = (const float*)d_in[8];
  const float* l2w  = (const float*)d_in[9];
  const float* l2b  = (const float*)d_in[10];
  const float* ln2w = (const float*)d_in[11];
  const float* ln2b = (const float*)d_in[12];

  char* ws = (char*)d_ws;
  size_t off = 0;
  auto take = [&](size_t bytes) {
    char* p = ws + off;
    off = (off + bytes + 255) & ~(size_t)255;
    return p;
  };
  bf16*  w_in_bf  = (bf16*) take((size_t)NL_*3*D_*D_*2);
  bf16*  w_out_bf = (bf16*) take((size_t)NL_*D_*D_*2);
  bf16*  w_l1_bf  = (bf16*) take((size_t)NL_*DFF_*D_*2);
  bf16*  w_l2_bf  = (bf16*) take((size_t)NL_*D_*DFF_*2);
  float* x_f      = (float*)take((size_t)M_*D_*4);
  bf16*  x_b      = (bf16*) take((size_t)M_*D_*2);
  bf16*  qkv_b    = (bf16*) take((size_t)M_*3*D_*2);
  bf16*  vt_b     = (bf16*) take((size_t)B_*H_*DH_*S_*2);
  bf16*  at_b     = (bf16*) take((size_t)M_*D_*2);
  bf16*  h_b      = (bf16*) take((size_t)M_*DFF_*2);
  float* tmp_f    = (float*)take((size_t)M_*D_*4);
  (void)ws_size; (void)in_sizes; (void)n_in;

  auto conv = [&](const float* s, bf16* d, size_t n) {
    int n4 = (int)(n >> 2);
    int grid = (n4 + 255) / 256; if (grid > 4096) grid = 4096;
    conv_kernel<<<grid, 256, 0, stream>>>((const float4*)s, (bf16x4*)d, n4);
  };
  conv(inw,  w_in_bf,  (size_t)NL_*3*D_*D_);
  conv(outw, w_out_bf, (size_t)NL_*D_*D_);
  conv(l1w,  w_l1_bf,  (size_t)NL_*DFF_*D_);
  conv(l2w,  w_l2_bf,  (size_t)NL_*D_*DFF_);
  init_x_kernel<<<4096, 256, 0, stream>>>((const float4*)x, (float4*)x_f,
                                          (bf16x4*)x_b, (int)((size_t)M_*D_ >> 2));

  for (int l = 0; l < NL_; ++l) {
    // qkv = x @ in_proj_w^T + b  [4096,3072]; V third written transposed
    gemm_bt_kernel<0,1,1><<<768, 256, 0, stream>>>(
        x_b, w_in_bf + (size_t)l*3*D_*D_, inb + (size_t)l*3*D_,
        nullptr, qkv_b, vt_b, 3*D_, D_, 24, 12, 8);
    // attention -> at_b [4096,1024] bf16 (1D grid, XCD swizzle)
    attn_kernel<<<1024, 256, 0, stream>>>(qkv_b, vt_b, at_b);
    // o = attn @ out_w^T + b -> tmp_f fp32; grid 8x32=256, patch 4x8
    gemm_bt_kernel<0,0,0><<<256, 256, 0, stream>>>(
        at_b, w_out_bf + (size_t)l*D_*D_, outb + (size_t)l*D_,
        tmp_f, nullptr, nullptr, D_, D_, 8, 4, 8);
    // x = LN(x + o)
    add_ln_kernel<<<M_, 256, 0, stream>>>(
        x_f, tmp_f, ln1w + (size_t)l*D_, ln1b + (size_t)l*D_,
        x_f, x_b, nullptr);
    // h = relu(x @ lin1^T + b) [4096,4096]; grid 32x32=1024, patch 16x8
    gemm_bt_kernel<1,1,0><<<1024, 256, 0, stream>>>(
        x_b, w_l1_bf + (size_t)l*DFF_*D_, l1b + (size_t)l*DFF_,
        nullptr, h_b, nullptr, DFF_, D_, 32, 16, 8);
    // f = h @ lin2^T + b -> tmp_f; grid 8x32=256, patch 4x8, K=4096
    gemm_bt_kernel<0,0,0><<<256, 256, 0, stream>>>(
        h_b, w_l2_bf + (size_t)l*D_*DFF_, l2b + (size_t)l*D_,
        tmp_f, nullptr, nullptr, D_, DFF_, 8, 4, 8);
    // x = LN(x + f); last layer also writes d_out
    add_ln_kernel<<<M_, 256, 0, stream>>>(
        x_f, tmp_f, ln2w + (size_t)l*D_, ln2b + (size_t)l*D_,
        x_f, x_b, (l == NL_-1) ? (float*)d_out : nullptr);
  }
}

// Round 6
// 1096.124 us; speedup vs baseline: 1.6545x; 1.1166x over previous
//
#include <hip/hip_runtime.h>
#include <stdint.h>

typedef __bf16 bf16;
typedef __bf16 bf16x8 __attribute__((ext_vector_type(8)));
typedef __bf16 bf16x4 __attribute__((ext_vector_type(4)));
typedef float  f32x4  __attribute__((ext_vector_type(4)));

#define B_   4
#define S_   1024
#define D_   1024
#define H_   16
#define DH_  64
#define DFF_ 4096
#define NL_  4
#define M_   (B_*S_)   // 4096 rows of activations

// ---------------------------------------------------------------------------
// async global->LDS copy, 16B per lane. LDS dest is wave-uniform base; lane i
// lands at base + i*16 bytes (guide §5 caveat).
// ---------------------------------------------------------------------------
__device__ __forceinline__ void async_copy16(const void* g, void* l) {
  __builtin_amdgcn_global_load_lds(
      (const __attribute__((address_space(1))) char*)(uintptr_t)g,
      (__attribute__((address_space(3))) char*)(uintptr_t)l,
      16, 0, 0);
}

// ---------------------------------------------------------------------------
// GEMM (BT form): C[M,N] = A[M,K_tot] @ W[N,K_tot]^T, 128x128 tile, 4 waves
// 2x2, mfma_f32_16x16x32_bf16, double-buffered LDS pipeline, XOR-swizzled
// coalesced global_load_lds staging (round 4/5: 0 conflicts, FETCH==footprint).
//
// BK template: 64 (16KB/buf/matrix, for 2-blocks/CU split-K GEMMs) or
//              32 (8KB/buf/matrix -> 32KB total, 3-4 blocks/CU for QKV/FF1).
// Swizzle: BK=64: chunk c8 ^ (row&7) (128B rows); BK=32: c4 ^ ((row>>1)&3)
// (64B rows) — both conflict-free under octet phasing.
//
// MODE: 1 = bf16 out + bias (+relu). 2 = fp32 split-K partial, no bias,
//       dest Cf + kz*M*N, K-range kz*Kc..+Kc (kz = L / bpk).
// QKV=1: tiles with bn >= 2048 (V third) written transposed to
//        VtOut[b][h][64][S] for the attention kernel.
// XCD patch swizzle (within each kz group): xcd = L&7, slot = L>>3, patch
// PN x PM; verified round 3 (FETCH 135 -> 49MB).
// ---------------------------------------------------------------------------
template<int RELU, int MODE, int QKV, int BK>
__global__ __launch_bounds__(256) void gemm_bt_kernel(
    const bf16* __restrict__ A,     // [M,Ktot] row-major bf16
    const bf16* __restrict__ W,     // [N,Ktot] row-major bf16
    const float* __restrict__ bias, // [N] (MODE 1)
    float* __restrict__ Cf,         // MODE 2
    bf16*  __restrict__ Cb,         // MODE 1
    bf16*  __restrict__ VtOut,      // QKV
    int N, int Ktot, int Kc, int gx, int PN, int PM, int bpk)
{
  constexpr int NI = (BK == 64) ? 4 : 2;    // staging issues per matrix/wave
  __shared__ bf16 As[2][128*BK];
  __shared__ bf16 Bs[2][128*BK];

  const int tid  = threadIdx.x;
  const int wave = tid >> 6;
  const int lane = tid & 63;
  const int wr = wave >> 1, wc = wave & 1;
  const int q4  = lane >> 4;
  const int l15 = lane & 15;

  // split-K + XCD-patch swizzle
  const int Lg  = blockIdx.x;
  const int kz  = Lg / bpk;
  const int L   = Lg % bpk;
  const int xcd = L & 7;
  const int s   = L >> 3;
  const int Gn  = gx / PN;
  const int bn = ((xcd % Gn)*PN + (s % PN)) << 7;
  const int bm = ((xcd / Gn)*PM + (s / PN)) << 7;
  const int kstart = kz * Kc;

  const bf16* agp[NI]; const bf16* wgp[NI];
  int ldsb[NI];
  if constexpr (BK == 64) {
    const int r_loc = lane >> 3, c8 = lane & 7;
#pragma unroll
    for (int j = 0; j < NI; ++j) {
      const int rr = wave*32 + j*8 + r_loc;
      const int ko = ((c8 ^ (rr & 7)) << 3);
      agp[j] = A + (size_t)(bm + rr)*Ktot + kstart + ko;
      wgp[j] = W + (size_t)(bn + rr)*Ktot + kstart + ko;
      ldsb[j] = (wave*32 + j*8) * 64;
    }
  } else {
    const int r_loc = lane >> 2, c4 = lane & 3;
#pragma unroll
    for (int j = 0; j < NI; ++j) {
      const int rr = wave*32 + j*16 + r_loc;
      const int ko = ((c4 ^ ((rr >> 1) & 3)) << 3);
      agp[j] = A + (size_t)(bm + rr)*Ktot + kstart + ko;
      wgp[j] = W + (size_t)(bn + rr)*Ktot + kstart + ko;
      ldsb[j] = (wave*32 + j*16) * 32;
    }
  }

  f32x4 acc[4][4] = {};
  const int steps = Kc / BK;

  auto stage = [&](int buf) {
#pragma unroll
    for (int j = 0; j < NI; ++j) {
      async_copy16(agp[j], &As[buf][ldsb[j]]);
      async_copy16(wgp[j], &Bs[buf][ldsb[j]]);
      agp[j] += BK; wgp[j] += BK;
    }
  };

  // precomputed read-slot xor terms
  const int sl32 = (l15 >> 1) & 3;   // BK=32: slot = q4 ^ sl32
  const int sl64 = l15 & 7;          // BK=64: slot = (kk*4+q4) ^ sl64

  auto compute = [&](int buf) {
    if constexpr (BK == 64) {
#pragma unroll
      for (int kk = 0; kk < 2; ++kk) {
        const int ch = (((kk << 2) | q4) ^ sl64) << 3;
        bf16x8 af[4], bfr[4];
#pragma unroll
        for (int rf = 0; rf < 4; ++rf)
          af[rf] = *(const bf16x8*)&As[buf][(wr*64 + rf*16 + l15)*64 + ch];
#pragma unroll
        for (int cf = 0; cf < 4; ++cf)
          bfr[cf] = *(const bf16x8*)&Bs[buf][(wc*64 + cf*16 + l15)*64 + ch];
#pragma unroll
        for (int rf = 0; rf < 4; ++rf)
#pragma unroll
          for (int cf = 0; cf < 4; ++cf)
            acc[rf][cf] = __builtin_amdgcn_mfma_f32_16x16x32_bf16(
                af[rf], bfr[cf], acc[rf][cf], 0, 0, 0);
      }
    } else {
      const int ch = (q4 ^ sl32) << 3;
      bf16x8 af[4], bfr[4];
#pragma unroll
      for (int rf = 0; rf < 4; ++rf)
        af[rf] = *(const bf16x8*)&As[buf][(wr*64 + rf*16 + l15)*32 + ch];
#pragma unroll
      for (int cf = 0; cf < 4; ++cf)
        bfr[cf] = *(const bf16x8*)&Bs[buf][(wc*64 + cf*16 + l15)*32 + ch];
#pragma unroll
      for (int rf = 0; rf < 4; ++rf)
#pragma unroll
        for (int cf = 0; cf < 4; ++cf)
          acc[rf][cf] = __builtin_amdgcn_mfma_f32_16x16x32_bf16(
              af[rf], bfr[cf], acc[rf][cf], 0, 0, 0);
    }
  };

  stage(0);
  __syncthreads();
  for (int k = 0; k < steps; ++k) {
    const int cur = k & 1;
    if (k + 1 < steps) stage(cur ^ 1);
    compute(cur);
    __syncthreads();   // drains next-buf loads; frees cur for restage
  }

  // epilogue: C/D layout col=lane&15, row=quad*4+reg (m89-verified)
  if (QKV && bn >= 2*D_) {
    // V third -> transposed Vt[b][h][64][S]; regs i are consecutive s
#pragma unroll
    for (int r = 0; r < 4; ++r) {
      const int row0 = bm + wr*64 + r*16 + q4*4;
      const int bidx = row0 >> 10, s0 = row0 & 1023;
#pragma unroll
      for (int c = 0; c < 4; ++c) {
        const int col  = bn + wc*64 + c*16 + l15;
        const int dcol = col - 2*D_;
        const int hh = dcol >> 6, dd = dcol & 63;
        const float bv = bias[col];
        bf16x4 pk;
#pragma unroll
        for (int i = 0; i < 4; ++i) pk[i] = (bf16)(acc[r][c][i] + bv);
        *(bf16x4*)&VtOut[((size_t)((bidx*H_ + hh)*64 + dd))*S_ + s0] = pk;
      }
    }
  } else if (MODE == 2) {
    float* Cfz = Cf + (size_t)kz * ((size_t)M_ * N);
#pragma unroll
    for (int r = 0; r < 4; ++r) {
      const int row0 = bm + wr*64 + r*16 + q4*4;
#pragma unroll
      for (int c = 0; c < 4; ++c) {
        const int col = bn + wc*64 + c*16 + l15;
#pragma unroll
        for (int i = 0; i < 4; ++i)
          Cfz[(size_t)(row0 + i)*N + col] = acc[r][c][i];
      }
    }
  } else {
#pragma unroll
    for (int r = 0; r < 4; ++r) {
      const int row0 = bm + wr*64 + r*16 + q4*4;
#pragma unroll
      for (int c = 0; c < 4; ++c) {
        const int col = bn + wc*64 + c*16 + l15;
        const float bv = bias[col];
#pragma unroll
        for (int i = 0; i < 4; ++i) {
          float v = acc[r][c][i] + bv;
          if (RELU) v = fmaxf(v, 0.f);
          Cb[(size_t)(row0 + i)*N + col] = (bf16)v;
        }
      }
    }
  }
}

// ---------------------------------------------------------------------------
// Flash-style block-causal attention (round 5 structure — left top-5):
// pre-transposed V, async staging, K/V double-buffer, XCD swizzle.
// ---------------------------------------------------------------------------
#define LP 72
__global__ __launch_bounds__(256) void attn_kernel(
    const bf16* __restrict__ qkv,  // [M][3072]: Q at +0, K at +1024
    const bf16* __restrict__ vt,   // [B*H][64][S]
    bf16* __restrict__ out)        // [M][D]
{
  const int L    = blockIdx.x;           // 0..1023
  const int xcd  = L & 7, slot = L >> 3;
  const int qb   = slot & 15;
  const int bh   = xcd*8 + (slot >> 4);
  const int b    = bh >> 4, h = bh & 15;
  const int tid  = threadIdx.x;
  const int wave = tid >> 6, lane = tid & 63;
  const int q4 = lane >> 4, l15 = lane & 15;
  const int r_loc = lane >> 3, c8 = lane & 7;

  __shared__ bf16 Qs[64*64];
  __shared__ bf16 Ks[2][64*64];
  __shared__ bf16 Vs[2][64*64];
  __shared__ bf16 Ps[4][16*LP];

  const size_t RS = 3*(size_t)D_;
  const bf16* qg = qkv + (size_t)(b*S_ + qb*64)*RS + h*64;
  const bf16* kg = qkv + (size_t)(b*S_)*RS + D_ + h*64;
  const bf16* vg = vt + (size_t)bh*64*S_;

#pragma unroll
  for (int j = 0; j < 2; ++j) {
    const int rr = wave*16 + j*8 + r_loc;
    const int ko = ((c8 ^ (rr & 7)) << 3);
    async_copy16(qg + (size_t)rr*RS + ko, &Qs[(wave*16 + j*8)*64]);
  }

#define STAGE_KV(KT, BUF)                                              \
  {                                                                    \
    _Pragma("unroll")                                                  \
    for (int j = 0; j < 2; ++j) {                                      \
      const int rr = wave*16 + j*8 + r_loc;                            \
      const int ko = ((c8 ^ (rr & 7)) << 3);                           \
      async_copy16(kg + (size_t)((KT)*64 + rr)*RS + ko,                \
                   &Ks[BUF][(wave*16 + j*8)*64]);                      \
      async_copy16(vg + (size_t)rr*S_ + (KT)*64 + ko,                  \
                   &Vs[BUF][(wave*16 + j*8)*64]);                      \
    }                                                                  \
  }

  f32x4 o_acc[4] = {};
  float m_i[4], l_i[4];
#pragma unroll
  for (int i = 0; i < 4; ++i) { m_i[i] = -1e30f; l_i[i] = 0.f; }
  const float scale = 0.125f;

  STAGE_KV(0, 0)
  __syncthreads();

  for (int kt = 0; kt <= qb; ++kt) {
    const int cur = kt & 1;
    if (kt < qb) {
      if (cur) STAGE_KV(kt+1, 0) else STAGE_KV(kt+1, 1)
    }

    f32x4 sc[4] = {};
#pragma unroll
    for (int kk = 0; kk < 2; ++kk) {
      const int go = ((((kk << 2) | q4)) ^ (l15 & 7)) << 3;
      bf16x8 aq = *(const bf16x8*)&Qs[(wave*16 + l15)*64 + go];
#pragma unroll
      for (int c = 0; c < 4; ++c) {
        bf16x8 bk = *(const bf16x8*)&Ks[cur][(c*16 + l15)*64 + go];
        sc[c] = __builtin_amdgcn_mfma_f32_16x16x32_bf16(aq, bk, sc[c], 0, 0, 0);
      }
    }
#pragma unroll
    for (int c = 0; c < 4; ++c)
#pragma unroll
      for (int i = 0; i < 4; ++i) sc[c][i] *= scale;

#pragma unroll
    for (int i = 0; i < 4; ++i) {
      float mx = -1e30f;
#pragma unroll
      for (int c = 0; c < 4; ++c) mx = fmaxf(mx, sc[c][i]);
#pragma unroll
      for (int off = 1; off < 16; off <<= 1) mx = fmaxf(mx, __shfl_xor(mx, off, 64));
      float m_new = fmaxf(m_i[i], mx);
      float alpha = __expf(m_i[i] - m_new);
      float rowsum = 0.f;
#pragma unroll
      for (int c = 0; c < 4; ++c) {
        float p = __expf(sc[c][i] - m_new);
        Ps[wave][(q4*4 + i)*LP + c*16 + l15] = (bf16)p;
        rowsum += p;
      }
#pragma unroll
      for (int off = 1; off < 16; off <<= 1) rowsum += __shfl_xor(rowsum, off, 64);
      l_i[i] = l_i[i]*alpha + rowsum;
      m_i[i] = m_new;
#pragma unroll
      for (int c = 0; c < 4; ++c) o_acc[c][i] *= alpha;
    }

#pragma unroll
    for (int kk = 0; kk < 2; ++kk) {
      bf16x8 ap = *(const bf16x8*)&Ps[wave][l15*LP + kk*32 + q4*8];
#pragma unroll
      for (int c = 0; c < 4; ++c) {
        const int go = ((((kk << 2) | q4)) ^ (l15 & 7)) << 3;
        bf16x8 bv = *(const bf16x8*)&Vs[cur][(c*16 + l15)*64 + go];
        o_acc[c] = __builtin_amdgcn_mfma_f32_16x16x32_bf16(ap, bv, o_acc[c], 0, 0, 0);
      }
    }
    __syncthreads();
  }
#undef STAGE_KV

  bf16* obase = out + ((size_t)(b*S_ + qb*64 + wave*16))*D_ + h*64;
#pragma unroll
  for (int i = 0; i < 4; ++i) {
    float inv = 1.f / l_i[i];
#pragma unroll
    for (int c = 0; c < 4; ++c)
      obase[(size_t)(q4*4 + i)*D_ + c*16 + l15] = (bf16)(o_acc[c][i]*inv);
  }
}

// ---------------------------------------------------------------------------
// fused: split-K reduce (2 partials) + bias + residual + LayerNorm (fp32)
// ---------------------------------------------------------------------------
__global__ __launch_bounds__(256) void add_ln_kernel(
    const float* __restrict__ xin, const float* __restrict__ parts,
    const float* __restrict__ ybias,
    const float* __restrict__ w, const float* __restrict__ bta,
    float* __restrict__ xout, bf16* __restrict__ xbf,
    float* __restrict__ extra)
{
  const int row = blockIdx.x;
  const int tid = threadIdx.x;
  const size_t base = (size_t)row * D_;
  const size_t PS = (size_t)M_ * D_;
  float v[4], sm = 0.f, ss = 0.f;
#pragma unroll
  for (int j = 0; j < 4; ++j) {
    int idx = tid + j*256;
    float y = ybias[idx] + parts[base + idx] + parts[PS + base + idx];
    v[j] = xin[base + idx] + y;
    sm += v[j]; ss += v[j]*v[j];
  }
#pragma unroll
  for (int off = 1; off < 64; off <<= 1) {
    sm += __shfl_xor(sm, off, 64);
    ss += __shfl_xor(ss, off, 64);
  }
  __shared__ float red[8];
  const int wave = tid >> 6, lane = tid & 63;
  if (lane == 0) { red[wave] = sm; red[4 + wave] = ss; }
  __syncthreads();
  sm = red[0] + red[1] + red[2] + red[3];
  ss = red[4] + red[5] + red[6] + red[7];
  const float mean = sm * (1.f/D_);
  const float var  = ss * (1.f/D_) - mean*mean;
  const float rstd = rsqrtf(var + 1e-5f);
#pragma unroll
  for (int j = 0; j < 4; ++j) {
    int idx = tid + j*256;
    float o = (v[j] - mean)*rstd*w[idx] + bta[idx];
    xout[base + idx] = o;
    xbf[base + idx]  = (bf16)o;
    if (extra) extra[base + idx] = o;
  }
}

// ---------------------------------------------------------------------------
__global__ __launch_bounds__(256) void conv_kernel(
    const float4* __restrict__ src, bf16x4* __restrict__ dst, int n4)
{
  int i = blockIdx.x*blockDim.x + threadIdx.x;
  const int stride = gridDim.x*blockDim.x;
  for (; i < n4; i += stride) {
    float4 f = src[i];
    bf16x4 o;
    o[0] = (bf16)f.x; o[1] = (bf16)f.y; o[2] = (bf16)f.z; o[3] = (bf16)f.w;
    dst[i] = o;
  }
}

__global__ __launch_bounds__(256) void init_x_kernel(
    const float4* __restrict__ src, float4* __restrict__ xf,
    bf16x4* __restrict__ xb, int n4)
{
  int i = blockIdx.x*blockDim.x + threadIdx.x;
  const int stride = gridDim.x*blockDim.x;
  for (; i < n4; i += stride) {
    float4 f = src[i];
    xf[i] = f;
    bf16x4 o;
    o[0] = (bf16)f.x; o[1] = (bf16)f.y; o[2] = (bf16)f.z; o[3] = (bf16)f.w;
    xb[i] = o;
  }
}

// ---------------------------------------------------------------------------
extern "C" void kernel_launch(void* const* d_in, const int* in_sizes, int n_in,
                              void* d_out, int out_size, void* d_ws, size_t ws_size,
                              hipStream_t stream) {
  const float* x    = (const float*)d_in[0];
  const float* inw  = (const float*)d_in[1];
  const float* inb  = (const float*)d_in[2];
  const float* outw = (const float*)d_in[3];
  const float* outb = (const float*)d_in[4];
  const float* ln1w = (const float*)d_in[5];
  const float* ln1b = (const float*)d_in[6];
  const float* l1w  = (const float*)d_in[7];
  const float* l1b  = (const float*)d_in[8];
  const float* l2w  = (const float*)d_in[9];
  const float* l2b  = (const float*)d_in[10];
  const float* ln2w = (const float*)d_in[11];
  const float* ln2b = (const float*)d_in[12];

  char* ws = (char*)d_ws;
  size_t off = 0;
  auto take = [&](size_t bytes) {
    char* p = ws + off;
    off = (off + bytes + 255) & ~(size_t)255;
    return p;
  };
  bf16*  w_in_bf  = (bf16*) take((size_t)NL_*3*D_*D_*2);
  bf16*  w_out_bf = (bf16*) take((size_t)NL_*D_*D_*2);
  bf16*  w_l1_bf  = (bf16*) take((size_t)NL_*DFF_*D_*2);
  bf16*  w_l2_bf  = (bf16*) take((size_t)NL_*D_*DFF_*2);
  float* x_f      = (float*)take((size_t)M_*D_*4);
  bf16*  x_b      = (bf16*) take((size_t)M_*D_*2);
  bf16*  qkv_b    = (bf16*) take((size_t)M_*3*D_*2);
  bf16*  vt_b     = (bf16*) take((size_t)B_*H_*DH_*S_*2);
  bf16*  at_b     = (bf16*) take((size_t)M_*D_*2);
  bf16*  h_b      = (bf16*) take((size_t)M_*DFF_*2);
  float* parts    = (float*)take((size_t)2*M_*D_*4);
  (void)ws_size; (void)in_sizes; (void)n_in;

  auto conv = [&](const float* s, bf16* d, size_t n) {
    int n4 = (int)(n >> 2);
    int grid = (n4 + 255) / 256; if (grid > 4096) grid = 4096;
    conv_kernel<<<grid, 256, 0, stream>>>((const float4*)s, (bf16x4*)d, n4);
  };
  conv(inw,  w_in_bf,  (size_t)NL_*3*D_*D_);
  conv(outw, w_out_bf, (size_t)NL_*D_*D_);
  conv(l1w,  w_l1_bf,  (size_t)NL_*DFF_*D_);
  conv(l2w,  w_l2_bf,  (size_t)NL_*D_*DFF_);
  init_x_kernel<<<4096, 256, 0, stream>>>((const float4*)x, (float4*)x_f,
                                          (bf16x4*)x_b, (int)((size_t)M_*D_ >> 2));

  for (int l = 0; l < NL_; ++l) {
    // qkv = x @ in_proj_w^T + b  [4096,3072]; BK=32 (3 blocks/CU); V -> Vt
    gemm_bt_kernel<0,1,1,32><<<768, 256, 0, stream>>>(
        x_b, w_in_bf + (size_t)l*3*D_*D_, inb + (size_t)l*3*D_,
        nullptr, qkv_b, vt_b, 3*D_, D_, D_, 24, 12, 8, 768);
    // attention -> at_b [4096,1024] bf16
    attn_kernel<<<1024, 256, 0, stream>>>(qkv_b, vt_b, at_b);
    // o partials = attn @ out_w^T  (split-K=2, BK=64, grid 512 = 2/CU)
    gemm_bt_kernel<0,2,0,64><<<512, 256, 0, stream>>>(
        at_b, w_out_bf + (size_t)l*D_*D_, nullptr,
        parts, nullptr, nullptr, D_, D_, D_/2, 8, 4, 8, 256);
    // x = LN(x + parts0 + parts1 + out_b)
    add_ln_kernel<<<M_, 256, 0, stream>>>(
        x_f, parts, outb + (size_t)l*D_,
        ln1w + (size_t)l*D_, ln1b + (size_t)l*D_, x_f, x_b, nullptr);
    // h = relu(x @ lin1^T + b) [4096,4096]; BK=32 (4 blocks/CU)
    gemm_bt_kernel<1,1,0,32><<<1024, 256, 0, stream>>>(
        x_b, w_l1_bf + (size_t)l*DFF_*D_, l1b + (size_t)l*DFF_,
        nullptr, h_b, nullptr, DFF_, D_, D_, 32, 16, 8, 1024);
    // f partials = h @ lin2^T  (split-K=2, BK=64, Kc=2048)
    gemm_bt_kernel<0,2,0,64><<<512, 256, 0, stream>>>(
        h_b, w_l2_bf + (size_t)l*D_*DFF_, nullptr,
        parts, nullptr, nullptr, D_, DFF_, DFF_/2, 8, 4, 8, 256);
    // x = LN(x + parts0 + parts1 + lin2_b); last layer writes d_out
    add_ln_kernel<<<M_, 256, 0, stream>>>(
        x_f, parts, l2b + (size_t)l*D_,
        ln2w + (size_t)l*D_, ln2b + (size_t)l*D_, x_f, x_b,
        (l == NL_-1) ? (float*)d_out : nullptr);
  }
}